// Round 8
// baseline (1027.580 us; speedup 1.0000x reference)
//
#include <hip/hip_runtime.h>
#include <cstdint>

// Problem constants: B=2, T=2048, C=1024, H=16, D=64, TOP_K=256
// feat_keep = ceil(D*min(TOP_K,T)/T) = ceil(64*256/2048) = 8
constexpr int Tn = 2048;
constexpr int Cn = 1024;
constexpr int Mn = 4096;          // B*T
constexpr int KKEEP = 256;        // row-wise top-k
constexpr int FKEEP = 8;          // feature top-k
constexpr unsigned U_NEG_INF = 0x007FFFFFu;  // umap(-inf)

constexpr int NW  = 4;            // waves per attn block
constexpr int NJA = 16;           // max col-groups for row A (tA < 1024)
constexpr int NJB = 32;           // max col-groups for row B (tB >= 1024)

// Order-preserving fp32 -> uint32 map (monotonic incl. +-inf; no NaNs here).
__device__ __forceinline__ unsigned umap(float f) {
    unsigned b = __float_as_uint(f);
    return (b & 0x80000000u) ? ~b : (b | 0x80000000u);
}
__device__ __forceinline__ float uunmap(unsigned u) {
    return __uint_as_float((u & 0x80000000u) ? (u ^ 0x80000000u) : ~u);
}

// fp32 -> bf16 (RNE).
__device__ __forceinline__ unsigned short f2bf(float f) {
    unsigned u = __float_as_uint(f);
    u += 0x7FFFu + ((u >> 16) & 1u);
    return (unsigned short)(u >> 16);
}
// Split fp32 into hi+lo bf16 pair.  x ~= hi + lo, ~17-bit effective mantissa.
struct bfpair { unsigned short h, l; };
__device__ __forceinline__ bfpair split_bf16(float x) {
    bfpair r;
    r.h = f2bf(x);
    r.l = f2bf(x - __uint_as_float((unsigned)r.h << 16));
    return r;
}

// Wave-uniform broadcasts on the SALU path (NOT ds_bpermute / LDS pipe).
__device__ __forceinline__ int   rli(int v, int l)   { return __builtin_amdgcn_readlane(v, l); }
__device__ __forceinline__ float rlf(float v, int l) {
    return __int_as_float(__builtin_amdgcn_readlane(__float_as_int(v), l));
}

typedef __attribute__((ext_vector_type(8))) short          short8v;  // 8 bf16
typedef __attribute__((ext_vector_type(8))) unsigned short ushort8v;
typedef __attribute__((ext_vector_type(4))) float          f32x4;    // MFMA acc

// ---------------------------------------------------------------------------
// Pre-split pass (R18): x -> XH/XL (d_out scratch), Wq/Wk/Wv -> packed hi/lo
// (KT-buffer scratch) ONCE.  Identical f2bf math -> downstream bit-identical.
// ---------------------------------------------------------------------------
constexpr size_t XCHUNK = (size_t)Mn * Cn / 8;      // 524288 8-elem chunks
constexpr size_t WCHUNK = (size_t)Cn * Cn / 8;      // 131072 per matrix
constexpr size_t WELEMS = (size_t)Cn * Cn;          // 1048576

__device__ __forceinline__ void split8(const float* s, unsigned short* dh,
                                       unsigned short* dl, size_t base)
{
    const float4 a = *(const float4*)&s[base], b = *(const float4*)&s[base + 4];
    ushort8v h, l; bfpair p;
    p = split_bf16(a.x); h[0] = p.h; l[0] = p.l;
    p = split_bf16(a.y); h[1] = p.h; l[1] = p.l;
    p = split_bf16(a.z); h[2] = p.h; l[2] = p.l;
    p = split_bf16(a.w); h[3] = p.h; l[3] = p.l;
    p = split_bf16(b.x); h[4] = p.h; l[4] = p.l;
    p = split_bf16(b.y); h[5] = p.h; l[5] = p.l;
    p = split_bf16(b.z); h[6] = p.h; l[6] = p.l;
    p = split_bf16(b.w); h[7] = p.h; l[7] = p.l;
    *(ushort8v*)&dh[base] = h;
    *(ushort8v*)&dl[base] = l;
}

__global__ __launch_bounds__(256)
void presplit(const float* __restrict__ x,  const float* __restrict__ Wq,
              const float* __restrict__ Wk, const float* __restrict__ Wv,
              unsigned short* __restrict__ XH, unsigned short* __restrict__ XL,
              unsigned short* __restrict__ WHL)
{
    const size_t cid = (size_t)blockIdx.x * 256 + threadIdx.x;
    if (cid < XCHUNK) {
        split8(x, XH, XL, cid * 8);
    } else {
        const size_t c2 = cid - XCHUNK;
        const int    z  = (int)(c2 / WCHUNK);        // 0..2
        const size_t e  = (c2 % WCHUNK) * 8;
        const float* src = (z == 0) ? Wq : (z == 1 ? Wk : Wv);
        unsigned short* dh = WHL + (size_t)z * 2 * WELEMS;
        unsigned short* dl = dh + WELEMS;
        split8(src, dh, dl, e);
    }
}

// ---------------------------------------------------------------------------
// QKV GEMM with PRE-SPLIT operands (bit-identical MFMA sequence).
// ---------------------------------------------------------------------------
__global__ __launch_bounds__(256, 2)
void gemm_qkv_ps(const unsigned short* __restrict__ XH,
                 const unsigned short* __restrict__ XL,
                 const unsigned short* __restrict__ WHL,
                 float* __restrict__ O0, float* __restrict__ O1,
                 float* __restrict__ O2)
{
    const int z = blockIdx.z;
    const unsigned short* WH = WHL + (size_t)z * 2 * WELEMS;
    const unsigned short* WL = WH + WELEMS;
    float* O = (z == 0) ? O0 : (z == 1 ? O1 : O2);

    __shared__ unsigned short Ah[128][40], Al[128][40];
    __shared__ unsigned short Bh[128][40], Bl[128][40];

    const int tid  = threadIdx.x;
    const int lane = tid & 63;
    const int wv   = tid >> 6;
    const int wm   = wv >> 1, wn = wv & 1;
    const int fm   = lane & 15;
    const int fq   = lane >> 4;
    const int m0   = blockIdx.y * 128;
    const int n0   = blockIdx.x * 128;

    f32x4 acc[4][4] = {};

    for (int k0 = 0; k0 < Cn; k0 += 32) {
        __syncthreads();
#pragma unroll
        for (int r = 0; r < 2; ++r) {
            const int idx = tid + r * 256;
            const int row = idx >> 2, c8 = (idx & 3) * 8;
            const size_t ao = (size_t)(m0 + row) * Cn + k0 + c8;
            const size_t bo = (size_t)(n0 + row) * Cn + k0 + c8;
            *(ushort8v*)&Ah[row][c8] = *(const ushort8v*)&XH[ao];
            *(ushort8v*)&Al[row][c8] = *(const ushort8v*)&XL[ao];
            *(ushort8v*)&Bh[row][c8] = *(const ushort8v*)&WH[bo];
            *(ushort8v*)&Bl[row][c8] = *(const ushort8v*)&WL[bo];
        }
        __syncthreads();

        short8v ah[4], al[4], bh[4], bl[4];
#pragma unroll
        for (int ti = 0; ti < 4; ++ti) {
            ah[ti] = *(const short8v*)&Ah[wm * 64 + ti * 16 + fm][fq * 8];
            al[ti] = *(const short8v*)&Al[wm * 64 + ti * 16 + fm][fq * 8];
            bh[ti] = *(const short8v*)&Bh[wn * 64 + ti * 16 + fm][fq * 8];
            bl[ti] = *(const short8v*)&Bl[wn * 64 + ti * 16 + fm][fq * 8];
        }
#pragma unroll
        for (int ti = 0; ti < 4; ++ti)
#pragma unroll
            for (int tj = 0; tj < 4; ++tj) {
                acc[ti][tj] = __builtin_amdgcn_mfma_f32_16x16x32_bf16(
                    ah[ti], bh[tj], acc[ti][tj], 0, 0, 0);
                acc[ti][tj] = __builtin_amdgcn_mfma_f32_16x16x32_bf16(
                    ah[ti], bl[tj], acc[ti][tj], 0, 0, 0);
                acc[ti][tj] = __builtin_amdgcn_mfma_f32_16x16x32_bf16(
                    al[ti], bh[tj], acc[ti][tj], 0, 0, 0);
            }
    }

#pragma unroll
    for (int ti = 0; ti < 4; ++ti)
#pragma unroll
        for (int tj = 0; tj < 4; ++tj)
#pragma unroll
            for (int r = 0; r < 4; ++r) {
                const int row = m0 + wm * 64 + ti * 16 + fq * 4 + r;
                const int col = n0 + wn * 64 + tj * 16 + fm;
                O[(size_t)row * Cn + col] = acc[ti][tj][r];
            }
}

// ---------------------------------------------------------------------------
// Out-proj GEMM: A pre-split (AOH/AOL from attn), W split on the fly.
// ---------------------------------------------------------------------------
__global__ __launch_bounds__(256, 2)
void gemm_out_ps(const unsigned short* __restrict__ AH,
                 const unsigned short* __restrict__ AL,
                 const float* __restrict__ Wo, float* __restrict__ O)
{
    __shared__ unsigned short Ah[128][40], Al[128][40];
    __shared__ unsigned short Bh[128][40], Bl[128][40];

    const int tid  = threadIdx.x;
    const int lane = tid & 63;
    const int wv   = tid >> 6;
    const int wm   = wv >> 1, wn = wv & 1;
    const int fm   = lane & 15;
    const int fq   = lane >> 4;
    const int m0   = blockIdx.y * 128;
    const int n0   = blockIdx.x * 128;

    f32x4 acc[4][4] = {};

    for (int k0 = 0; k0 < Cn; k0 += 32) {
        __syncthreads();
#pragma unroll
        for (int r = 0; r < 2; ++r) {
            const int idx = tid + r * 256;
            const int row = idx >> 2, c8 = (idx & 3) * 8;
            const size_t ao = (size_t)(m0 + row) * Cn + k0 + c8;
            *(ushort8v*)&Ah[row][c8] = *(const ushort8v*)&AH[ao];
            *(ushort8v*)&Al[row][c8] = *(const ushort8v*)&AL[ao];
            {
                const float* s = &Wo[(size_t)(n0 + row) * Cn + k0 + c8];
                const float4 x0 = *(const float4*)s, x1 = *(const float4*)(s + 4);
                ushort8v h, l;
                bfpair p;
                p = split_bf16(x0.x); h[0] = p.h; l[0] = p.l;
                p = split_bf16(x0.y); h[1] = p.h; l[1] = p.l;
                p = split_bf16(x0.z); h[2] = p.h; l[2] = p.l;
                p = split_bf16(x0.w); h[3] = p.h; l[3] = p.l;
                p = split_bf16(x1.x); h[4] = p.h; l[4] = p.l;
                p = split_bf16(x1.y); h[5] = p.h; l[5] = p.l;
                p = split_bf16(x1.z); h[6] = p.h; l[6] = p.l;
                p = split_bf16(x1.w); h[7] = p.h; l[7] = p.l;
                *(ushort8v*)&Bh[row][c8] = h;
                *(ushort8v*)&Bl[row][c8] = l;
            }
        }
        __syncthreads();

        short8v ah[4], al[4], bh[4], bl[4];
#pragma unroll
        for (int ti = 0; ti < 4; ++ti) {
            ah[ti] = *(const short8v*)&Ah[wm * 64 + ti * 16 + fm][fq * 8];
            al[ti] = *(const short8v*)&Al[wm * 64 + ti * 16 + fm][fq * 8];
            bh[ti] = *(const short8v*)&Bh[wn * 64 + ti * 16 + fm][fq * 8];
            bl[ti] = *(const short8v*)&Bl[wn * 64 + ti * 16 + fm][fq * 8];
        }
#pragma unroll
        for (int ti = 0; ti < 4; ++ti)
#pragma unroll
            for (int tj = 0; tj < 4; ++tj) {
                acc[ti][tj] = __builtin_amdgcn_mfma_f32_16x16x32_bf16(
                    ah[ti], bh[tj], acc[ti][tj], 0, 0, 0);
                acc[ti][tj] = __builtin_amdgcn_mfma_f32_16x16x32_bf16(
                    ah[ti], bl[tj], acc[ti][tj], 0, 0, 0);
                acc[ti][tj] = __builtin_amdgcn_mfma_f32_16x16x32_bf16(
                    al[ti], bh[tj], acc[ti][tj], 0, 0, 0);
            }
    }

#pragma unroll
    for (int ti = 0; ti < 4; ++ti)
#pragma unroll
        for (int tj = 0; tj < 4; ++tj)
#pragma unroll
            for (int r = 0; r < 4; ++r) {
                const int row = m0 + wm * 64 + ti * 16 + fq * 4 + r;
                const int col = n0 + wn * 64 + tj * 16 + fm;
                O[(size_t)row * Cn + col] = acc[ti][tj][r];
            }
}

// ---------------------------------------------------------------------------
// Feature sparsify for Q and V (in place).
// ---------------------------------------------------------------------------
__global__ __launch_bounds__(256)
void sparsify_topk(float* __restrict__ Q, float* __restrict__ V)
{
    const int wid  = (blockIdx.x * 256 + threadIdx.x) >> 6;  // global wave id
    const int lane = threadIdx.x & 63;
    const int tensor = wid >> 16;        // 0=Q, 1=V
    const int vec    = wid & 65535;
    float* base = tensor ? V : Q;

    const size_t off = (size_t)vec * 64 + lane;
    const float v = base[off];
    const float a = fabsf(v);

    int cnt = 0;   // # strictly greater than mine
#pragma unroll
    for (int j = 0; j < 64; ++j) {
        const float aj = __shfl(a, j);
        cnt += (aj > a) ? 1 : 0;
    }
    float cand = (cnt < FKEEP) ? a : 3.402823466e38f;
#pragma unroll
    for (int o = 32; o; o >>= 1) cand = fminf(cand, __shfl_xor(cand, o));
    base[off] = (a >= cand) ? v : 0.0f;
}

// ---------------------------------------------------------------------------
// K sparsify + transpose: K[b][t][h][d] -> KT[bh][d][t].
// ---------------------------------------------------------------------------
__global__ __launch_bounds__(256)
void sparsify_k_t(const float* __restrict__ K, float* __restrict__ KT)
{
    __shared__ float tile[64][65];       // [t-row][d], pad 65

    const int tid = threadIdx.x;
    const int w = tid >> 6, lane = tid & 63;
    const int tt = blockIdx.x;           // t-tile 0..31
    const int bh = blockIdx.y;           // 0..31
    const int b = bh >> 4, h = bh & 15;
    const int t0 = tt * 64;

#pragma unroll
    for (int k = 0; k < 4; ++k) {
        const int c = tid + k * 256;     // 0..1023 float4-chunks
        const int row = c >> 4, off = (c & 15) * 4;
        const float4 v4 = *(const float4*)
            &K[(size_t)((b * Tn + t0 + row) * 16 + h) * 64 + off];
        tile[row][off + 0] = v4.x; tile[row][off + 1] = v4.y;
        tile[row][off + 2] = v4.z; tile[row][off + 3] = v4.w;
    }
    __syncthreads();

#pragma unroll 1
    for (int r = w; r < 64; r += 4) {
        const float v = tile[r][lane];
        const float a = fabsf(v);
        int cnt = 0;
#pragma unroll
        for (int j = 0; j < 64; ++j) {
            const float aj = __shfl(a, j);
            cnt += (aj > a) ? 1 : 0;
        }
        float cand = (cnt < FKEEP) ? a : 3.402823466e38f;
#pragma unroll
        for (int o = 32; o; o >>= 1) cand = fminf(cand, __shfl_xor(cand, o));
        tile[r][lane] = (a >= cand) ? v : 0.0f;
    }
    __syncthreads();

#pragma unroll
    for (int k = 0; k < 16; ++k) {
        const int d = w + k * 4;
        KT[(((size_t)bh * 64 + d) << 11) + t0 + lane] = tile[lane][d];
    }
}

// ---------------------------------------------------------------------------
// Attention core, R19: TWO ROWS PER WAVE (tA, 2047-tA) with instruction-level
// interleaving of the two independent row pipelines (score quads, radix
// levels via active-flags, PV blocks).  Rationale: occupancy is pinned at
// ~12 waves/CU (R15/R16 falsified every resource knob) and per-wave wall
// time is ~5x its instruction work -> raise per-wave ILP instead.  Pairing
// t with 2047-t makes per-wave work EXACTLY constant (2049 cols).
// Also: (col,p) packed as uint2 in LDS; PV reads one ds_read_b64 broadcast
// per 4 cols (was 2 bpermutes).  Per-row math order identical -> bit-exact.
// LDS: hist 2x4KB + cpk 2x8KB = 24576 B.
// ---------------------------------------------------------------------------
__global__ __launch_bounds__(256, 4)
void attn_kernel(const float* __restrict__ Qm, const float* __restrict__ KTm,
                 const float* __restrict__ Vm,
                 unsigned short* __restrict__ AOH,
                 unsigned short* __restrict__ AOL)
{
    __shared__ unsigned histA[NW * 256], histB[NW * 256];
    __shared__ uint2    cpkA[NW * 256], cpkB[NW * 256];

    const int tid  = threadIdx.x;
    const int w    = tid >> 6;
    const int lane = tid & 63;
    const int bh   = blockIdx.y;             // 0..31
    const int b    = bh >> 4;
    const int h    = bh & 15;
    const int tA   = blockIdx.x * NW + w;    // 0..1023
    const int tB   = (Tn - 1) - tA;          // 1024..2047
    const size_t rowoffA = ((size_t)(b * Tn + tA) << 10) + (h << 6);
    const size_t rowoffB = ((size_t)(b * Tn + tB) << 10) + (h << 6);
    const size_t kvoff   = ((size_t)(b * Tn) << 10) + (h << 6);

    const float qA = Qm[rowoffA + lane];
    const float qB = Qm[rowoffB + lane];
    const float qscA = qA * 0.125f, qscB = qB * 0.125f;
    const unsigned long long nzmA = __ballot(qA != 0.0f);
    const unsigned long long nzmB = __ballot(qB != 0.0f);
    const int nnzA = __popcll(nzmA), nnzB = __popcll(nzmB);

    const int njA = (tA >> 6) + 1;           // 1..16
    const int njB = (tB >> 6) + 1;           // 17..32
    const float* ktb = KTm + ((size_t)bh << 17);

    const bool doselA = (tA >= KKEEP);       // B always selects (tB >= 1024)
    unsigned* hrowA = histA + w * 256;
    unsigned* hrowB = histB + w * 256;
    hrowA[lane] = 0; hrowA[64 + lane] = 0; hrowA[128 + lane] = 0; hrowA[192 + lane] = 0;
    hrowB[lane] = 0; hrowB[64 + lane] = 0; hrowB[128 + lane] = 0; hrowB[192 + lane] = 0;
    __asm__ volatile("s_waitcnt lgkmcnt(0)" ::: "memory");

    unsigned svA[NJA], svB[NJB];
    unsigned rmA = 0u, rmB = 0u;

    if (nnzA == 8 && nnzB == 8) {
        float mqA[8], mqB[8]; int moA[8], moB[8];
        {
            unsigned long long mm = nzmA;
#pragma unroll
            for (int i = 0; i < 8; ++i) {
                const int m = (int)__builtin_ctzll(mm); mm &= mm - 1;
                mqA[i] = rlf(qscA, m); moA[i] = m << 11;
            }
        }
        {
            unsigned long long mm = nzmB;
#pragma unroll
            for (int i = 0; i < 8; ++i) {
                const int m = (int)__builtin_ctzll(mm); mm &= mm - 1;
                mqB[i] = rlf(qscB, m); moB[i] = m << 11;
            }
        }
#pragma unroll
        for (int jq = 0; jq < 8; ++jq) {
            const int j0 = jq * 4;
            // ---- row B quad jq ----
            if (j0 < njB) {
                const int c0 = (j0 << 6) + lane;
                if (j0 + 4 <= njB) {
                    float s0 = 0, s1 = 0, s2 = 0, s3 = 0;
#pragma unroll
                    for (int i = 0; i < 8; ++i) {
                        const float* kp = ktb + moB[i];
                        s0 += mqB[i] * kp[c0];
                        s1 += mqB[i] * kp[c0 + 64];
                        s2 += mqB[i] * kp[c0 + 128];
                        s3 += mqB[i] * kp[c0 + 192];
                    }
                    const unsigned v0 = (c0       <= tB) ? umap(s0) : U_NEG_INF;
                    const unsigned v1 = (c0 +  64 <= tB) ? umap(s1) : U_NEG_INF;
                    const unsigned v2 = (c0 + 128 <= tB) ? umap(s2) : U_NEG_INF;
                    const unsigned v3 = (c0 + 192 <= tB) ? umap(s3) : U_NEG_INF;
                    svB[j0] = v0; svB[j0 + 1] = v1; svB[j0 + 2] = v2; svB[j0 + 3] = v3;
                    unsigned m01 = (v0 > v1) ? v0 : v1;
                    unsigned m23 = (v2 > v3) ? v2 : v3;
                    m01 = (m01 > m23) ? m01 : m23;
                    rmB = (m01 > rmB) ? m01 : rmB;
                    atomicAdd(&hrowB[v0 >> 24], 1u);
                    atomicAdd(&hrowB[v1 >> 24], 1u);
                    atomicAdd(&hrowB[v2 >> 24], 1u);
                    atomicAdd(&hrowB[v3 >> 24], 1u);
                } else {
#pragma unroll
                    for (int k = 0; k < 4; ++k) {
                        const int j = j0 + k;
                        if (j < njB) {
                            const int col = (j << 6) + lane;
                            float s = 0;
#pragma unroll
                            for (int i = 0; i < 8; ++i) s += mqB[i] * ktb[moB[i] + col];
                            const unsigned v = (col <= tB) ? umap(s) : U_NEG_INF;
                            svB[j] = v;
                            rmB = (v > rmB) ? v : rmB;
                            atomicAdd(&hrowB[v >> 24], 1u);
                        } else svB[j] = U_NEG_INF;
                    }
                }
            } else {
                svB[j0] = U_NEG_INF; svB[j0 + 1] = U_NEG_INF;
                svB[j0 + 2] = U_NEG_INF; svB[j0 + 3] = U_NEG_INF;
            }
            // ---- row A quad jq (first 4 only) ----
            if (jq < 4) {
                if (j0 < njA) {
                    const int c0 = (j0 << 6) + lane;
                    if (j0 + 4 <= njA) {
                        float s0 = 0, s1 = 0, s2 = 0, s3 = 0;
#pragma unroll
                        for (int i = 0; i < 8; ++i) {
                            const float* kp = ktb + moA[i];
                            s0 += mqA[i] * kp[c0];
                            s1 += mqA[i] * kp[c0 + 64];
                            s2 += mqA[i] * kp[c0 + 128];
                            s3 += mqA[i] * kp[c0 + 192];
                        }
                        const unsigned v0 = (c0       <= tA) ? umap(s0) : U_NEG_INF;
                        const unsigned v1 = (c0 +  64 <= tA) ? umap(s1) : U_NEG_INF;
                        const unsigned v2 = (c0 + 128 <= tA) ? umap(s2) : U_NEG_INF;
                        const unsigned v3 = (c0 + 192 <= tA) ? umap(s3) : U_NEG_INF;
                        svA[j0] = v0; svA[j0 + 1] = v1; svA[j0 + 2] = v2; svA[j0 + 3] = v3;
                        unsigned m01 = (v0 > v1) ? v0 : v1;
                        unsigned m23 = (v2 > v3) ? v2 : v3;
                        m01 = (m01 > m23) ? m01 : m23;
                        rmA = (m01 > rmA) ? m01 : rmA;
                        if (doselA) {
                            atomicAdd(&hrowA[v0 >> 24], 1u);
                            atomicAdd(&hrowA[v1 >> 24], 1u);
                            atomicAdd(&hrowA[v2 >> 24], 1u);
                            atomicAdd(&hrowA[v3 >> 24], 1u);
                        }
                    } else {
#pragma unroll
                        for (int k = 0; k < 4; ++k) {
                            const int j = j0 + k;
                            if (j < njA) {
                                const int col = (j << 6) + lane;
                                float s = 0;
#pragma unroll
                                for (int i = 0; i < 8; ++i) s += mqA[i] * ktb[moA[i] + col];
                                const unsigned v = (col <= tA) ? umap(s) : U_NEG_INF;
                                svA[j] = v;
                                rmA = (v > rmA) ? v : rmA;
                                if (doselA) atomicAdd(&hrowA[v >> 24], 1u);
                            } else svA[j] = U_NEG_INF;
                        }
                    }
                } else {
                    svA[j0] = U_NEG_INF; svA[j0 + 1] = U_NEG_INF;
                    svA[j0 + 2] = U_NEG_INF; svA[j0 + 3] = U_NEG_INF;
                }
            }
        }
    } else {
        // generic fallback (magnitude ties -> nnz != 8): rare, wave-uniform
#pragma unroll
        for (int j = 0; j < NJA; ++j) {
            if (j >= njA) { svA[j] = U_NEG_INF; continue; }
            const int col = (j << 6) + lane;
            float s = 0.0f;
            unsigned long long mm = nzmA;
            while (mm) {
                const int m = (int)__builtin_ctzll(mm); mm &= mm - 1;
                s += rlf(qscA, m) * ktb[((size_t)m << 11) + col];
            }
            const unsigned v = (col <= tA) ? umap(s) : U_NEG_INF;
            svA[j] = v;
            rmA = (v > rmA) ? v : rmA;
            if (doselA) atomicAdd(&hrowA[v >> 24], 1u);
        }
#pragma unroll
        for (int j = 0; j < NJB; ++j) {
            if (j >= njB) { svB[j] = U_NEG_INF; continue; }
            const int col = (j << 6) + lane;
            float s = 0.0f;
            unsigned long long mm = nzmB;
            while (mm) {
                const int m = (int)__builtin_ctzll(mm); mm &= mm - 1;
                s += rlf(qscB, m) * ktb[((size_t)m << 11) + col];
            }
            const unsigned v = (col <= tB) ? umap(s) : U_NEG_INF;
            svB[j] = v;
            rmB = (v > rmB) ? v : rmB;
            atomicAdd(&hrowB[v >> 24], 1u);
        }
    }

    // ---- row maxes (two independent shfl chains, interleaved) ----
#pragma unroll
    for (int o = 32; o; o >>= 1) {
        const unsigned a2 = __shfl_xor(rmA, o);
        const unsigned b2 = __shfl_xor(rmB, o);
        rmA = (a2 > rmA) ? a2 : rmA;
        rmB = (b2 > rmB) ? b2 : rmB;
    }
    const float fmA = uunmap(rmA), fmB = uunmap(rmB);

    // ---- radix-256 kth select, both rows interleaved via active flags ----
    unsigned curA = U_NEG_INF, curB = U_NEG_INF;
    {
        bool actA = doselA, actB = true;
        unsigned prefA = 0u, pmaA = 0u, rA = KKEEP;
        unsigned prefB = 0u, pmaB = 0u, rB = KKEEP;
#pragma unroll 1
        for (int level = 0; level < 4; ++level) {
            const int sh = 24 - 8 * level;
            if (level) {
                if (actA) { hrowA[lane] = 0; hrowA[64 + lane] = 0;
                            hrowA[128 + lane] = 0; hrowA[192 + lane] = 0; }
                if (actB) { hrowB[lane] = 0; hrowB[64 + lane] = 0;
                            hrowB[128 + lane] = 0; hrowB[192 + lane] = 0; }
                __asm__ volatile("s_waitcnt lgkmcnt(0)" ::: "memory");
                if (actA) {
#pragma unroll
                    for (int j = 0; j < NJA; ++j) {
                        if (j < njA) {
                            const int col = (j << 6) + lane;
                            const unsigned v = svA[j];
                            if (col <= tA && (v & pmaA) == prefA)
                                atomicAdd(&hrowA[(v >> sh) & 255u], 1u);
                        }
                    }
                }
                if (actB) {
#pragma unroll
                    for (int j = 0; j < NJB; ++j) {
                        if (j < njB) {
                            const int col = (j << 6) + lane;
                            const unsigned v = svB[j];
                            if (col <= tB && (v & pmaB) == prefB)
                                atomicAdd(&hrowB[(v >> sh) & 255u], 1u);
                        }
                    }
                }
            }
            __asm__ volatile("s_waitcnt lgkmcnt(0)" ::: "memory");
            if (actA) {
                const uint4 hv = *(const uint4*)&hrowA[lane * 4];
                const unsigned ls = hv.x + hv.y + hv.z + hv.w;
                unsigned sfx = ls;
#pragma unroll
                for (int off = 1; off < 64; off <<= 1) {
                    const unsigned tt2 = __shfl_down(sfx, off);
                    if (lane + off < 64) sfx += tt2;
                }
                const unsigned excl = sfx - ls;
                const unsigned c3 = excl + hv.w, c2 = c3 + hv.z,
                               c1 = c2 + hv.y,  c0 = c1 + hv.x;
                int bsel = -1; unsigned csel = 0, cnext = 0;
                if      (c3 >= rA) { bsel = 4 * lane + 3; csel = c3; cnext = excl; }
                else if (c2 >= rA) { bsel = 4 * lane + 2; csel = c2; cnext = c3; }
                else if (c1 >= rA) { bsel = 4 * lane + 1; csel = c1; cnext = c2; }
                else if (c0 >= rA) { bsel = 4 * lane + 0; csel = c0; cnext = c1; }
                int B = bsel;
#pragma unroll
                for (int off = 32; off; off >>= 1) {
                    const int ob = __shfl_xor(B, off);
                    B = (ob > B) ? ob : B;
                }
                const unsigned cB  = (unsigned)__shfl((int)csel,  B >> 2);
                const unsigned cB1 = (unsigned)__shfl((int)cnext, B >> 2);
                prefA |= (unsigned)B << sh;
                pmaA  |= 255u << sh;
                if (cB == rA || level == 3) { curA = prefA; actA = false; }
                else rA -= cB1;
            }
            if (actB) {
                const uint4 hv = *(const uint4*)&hrowB[lane * 4];
                const unsigned ls = hv.x + hv.y + hv.z + hv.w;
                unsigned sfx = ls;
#pragma unroll
                for (int off = 1; off < 64; off <<= 1) {
                    const unsigned tt2 = __shfl_down(sfx, off);
                    if (lane + off < 64) sfx += tt2;
                }
                const unsigned excl = sfx - ls;
                const unsigned c3 = excl + hv.w, c2 = c3 + hv.z,
                               c1 = c2 + hv.y,  c0 = c1 + hv.x;
                int bsel = -1; unsigned csel = 0, cnext = 0;
                if      (c3 >= rB) { bsel = 4 * lane + 3; csel = c3; cnext = excl; }
                else if (c2 >= rB) { bsel = 4 * lane + 2; csel = c2; cnext = c3; }
                else if (c1 >= rB) { bsel = 4 * lane + 1; csel = c1; cnext = c2; }
                else if (c0 >= rB) { bsel = 4 * lane + 0; csel = c0; cnext = c1; }
                int B = bsel;
#pragma unroll
                for (int off = 32; off; off >>= 1) {
                    const int ob = __shfl_xor(B, off);
                    B = (ob > B) ? ob : B;
                }
                const unsigned cB  = (unsigned)__shfl((int)csel,  B >> 2);
                const unsigned cB1 = (unsigned)__shfl((int)cnext, B >> 2);
                prefB |= (unsigned)B << sh;
                pmaB  |= 255u << sh;
                if (cB == rB || level == 3) { curB = prefB; actB = false; }
                else rB -= cB1;
            }
            if (!actA && !actB) break;
        }
    }

    // ---- softmax + compaction per row: packed (col, p) uint2 into LDS ----
    uint2* cpA = cpkA + w * 256;
    uint2* cpB = cpkB + w * 256;
    float invA, invB;
    int cntA = 0, cntB = 0;
    bool ovfA = false, ovfB = false;
    {
        float ps = 0.0f; int cnt = 0;
#pragma unroll
        for (int j = 0; j < NJA; ++j) {
            if (j >= njA) continue;
            const int col = (j << 6) + lane;
            float pv = 0.0f;
            const unsigned uv = svA[j];
            if (col <= tA && uv >= curA) pv = __expf(uunmap(uv) - fmA);
            ps += pv;
            const unsigned long long m = __ballot(pv > 0.0f);
            const int c = __popcll(m);
            if (cnt + c <= 256) {
                if (pv > 0.0f) {
                    const int pos = cnt + __popcll(m & ((1ull << lane) - 1ull));
                    cpA[pos] = make_uint2((unsigned)col, __float_as_uint(pv));
                }
            } else ovfA = true;
            cnt += c;
        }
#pragma unroll
        for (int o = 32; o; o >>= 1) ps += __shfl_xor(ps, o);
        invA = 1.0f / ps; cntA = cnt;
#pragma unroll
        for (int blk = 0; blk < 4; ++blk) {
            const int idx = blk * 64 + lane;
            if (idx >= cntA) cpA[idx] = make_uint2(0u, 0u);
        }
    }
    {
        float ps = 0.0f; int cnt = 0;
#pragma unroll
        for (int j = 0; j < NJB; ++j) {
            if (j >= njB) continue;
            const int col = (j << 6) + lane;
            float pv = 0.0f;
            const unsigned uv = svB[j];
            if (col <= tB && uv >= curB) pv = __expf(uunmap(uv) - fmB);
            ps += pv;
            const unsigned long long m = __ballot(pv > 0.0f);
            const int c = __popcll(m);
            if (cnt + c <= 256) {
                if (pv > 0.0f) {
                    const int pos = cnt + __popcll(m & ((1ull << lane) - 1ull));
                    cpB[pos] = make_uint2((unsigned)col, __float_as_uint(pv));
                }
            } else ovfB = true;
            cnt += c;
        }
#pragma unroll
        for (int o = 32; o; o >>= 1) ps += __shfl_xor(ps, o);
        invB = 1.0f / ps; cntB = cnt;
#pragma unroll
        for (int blk = 0; blk < 4; ++blk) {
            const int idx = blk * 64 + lane;
            if (idx >= cntB) cpB[idx] = make_uint2(0u, 0u);
        }
    }

    // ---- PV: 4 dims/lane, 4 col-subgroups; A and B blocks interleaved ----
    const int g  = lane >> 4;
    const int d0 = (lane & 15) * 4;
    const float* __restrict__ vb4 = Vm + kvoff + d0;
    float axA = 0, ayA = 0, azA = 0, awA = 0;
    float axB = 0, ayB = 0, azB = 0, awB = 0;
#pragma unroll
    for (int blk = 0; blk < 4; ++blk) {
        const bool doA = !ovfA && (cntA > blk * 64);
        const bool doB = !ovfB && (cntB > blk * 64);
        if (doA) {
#pragma unroll
            for (int j = 0; j < 16; ++j) {
                const uint2 e = cpA[blk * 64 + 4 * j + g];
                const float p = __uint_as_float(e.y);
                const float4 v4 = *(const float4*)&vb4[(size_t)e.x * Cn];
                axA += p * v4.x; ayA += p * v4.y;
                azA += p * v4.z; awA += p * v4.w;
            }
        }
        if (doB) {
#pragma unroll
            for (int j = 0; j < 16; ++j) {
                const uint2 e = cpB[blk * 64 + 4 * j + g];
                const float p = __uint_as_float(e.y);
                const float4 v4 = *(const float4*)&vb4[(size_t)e.x * Cn];
                axB += p * v4.x; ayB += p * v4.y;
                azB += p * v4.z; awB += p * v4.w;
            }
        }
    }
    // cross-subgroup reduce (both rows interleaved)
#pragma unroll
    for (int o = 16; o <= 32; o <<= 1) {
        axA += __shfl_xor(axA, o); ayA += __shfl_xor(ayA, o);
        azA += __shfl_xor(azA, o); awA += __shfl_xor(awA, o);
        axB += __shfl_xor(axB, o); ayB += __shfl_xor(ayB, o);
        azB += __shfl_xor(azB, o); awB += __shfl_xor(awB, o);
    }
    if (!ovfA && g == 0) {
        const float vx = axA * invA, vy = ayA * invA,
                    vz = azA * invA, vw = awA * invA;
        const bfpair px = split_bf16(vx), py = split_bf16(vy),
                     pz = split_bf16(vz), pw = split_bf16(vw);
        ushort4 hq, lq;
        hq.x = px.h; hq.y = py.h; hq.z = pz.h; hq.w = pw.h;
        lq.x = px.l; lq.y = py.l; lq.z = pz.l; lq.w = pw.l;
        *(ushort4*)&AOH[rowoffA + d0] = hq;
        *(ushort4*)&AOL[rowoffA + d0] = lq;
    }
    if (!ovfB && g == 0) {
        const float vx = axB * invB, vy = ayB * invB,
                    vz = azB * invB, vw = awB * invB;
        const bfpair px = split_bf16(vx), py = split_bf16(vy),
                     pz = split_bf16(vz), pw = split_bf16(vw);
        ushort4 hq, lq;
        hq.x = px.h; hq.y = py.h; hq.z = pz.h; hq.w = pw.h;
        lq.x = px.l; lq.y = py.l; lq.z = pz.l; lq.w = pw.l;
        *(ushort4*)&AOH[rowoffB + d0] = hq;
        *(ushort4*)&AOL[rowoffB + d0] = lq;
    }

    // ---- tie-overflow fallbacks (rare), per row ----
    if (ovfA) {
        const float* __restrict__ vcol = Vm + kvoff + lane;
        float acc = 0.0f;
#pragma unroll
        for (int j = 0; j < NJA; ++j) {
            if (j >= njA) continue;
            const int col = (j << 6) + lane;
            float pv = 0.0f;
            const unsigned uv = svA[j];
            if (col <= tA && uv >= curA) pv = __expf(uunmap(uv) - fmA);
            unsigned long long m = __ballot(pv > 0.0f);
            const int cb = j << 6;
            while (m) {
                const int l0 = __builtin_ctzll(m); m &= m - 1;
                const float w0 = __shfl(pv, l0);
                const float v0 = vcol[(size_t)(cb + l0) * Cn];
                float w1 = 0.0f, v1 = 0.0f;
                if (m) {
                    const int l1 = __builtin_ctzll(m); m &= m - 1;
                    w1 = __shfl(pv, l1);
                    v1 = vcol[(size_t)(cb + l1) * Cn];
                }
                acc += w0 * v0;
                acc += w1 * v1;
            }
        }
        const float v = acc * invA;
        const bfpair p = split_bf16(v);
        AOH[rowoffA + lane] = p.h;
        AOL[rowoffA + lane] = p.l;
    }
    if (ovfB) {
        const float* __restrict__ vcol = Vm + kvoff + lane;
        float acc = 0.0f;
#pragma unroll
        for (int j = 0; j < NJB; ++j) {
            if (j >= njB) continue;
            const int col = (j << 6) + lane;
            float pv = 0.0f;
            const unsigned uv = svB[j];
            if (col <= tB && uv >= curB) pv = __expf(uunmap(uv) - fmB);
            unsigned long long m = __ballot(pv > 0.0f);
            const int cb = j << 6;
            while (m) {
                const int l0 = __builtin_ctzll(m); m &= m - 1;
                const float w0 = __shfl(pv, l0);
                const float v0 = vcol[(size_t)(cb + l0) * Cn];
                float w1 = 0.0f, v1 = 0.0f;
                if (m) {
                    const int l1 = __builtin_ctzll(m); m &= m - 1;
                    w1 = __shfl(pv, l1);
                    v1 = vcol[(size_t)(cb + l1) * Cn];
                }
                acc += w0 * v0;
                acc += w1 * v1;
            }
        }
        const float v = acc * invB;
        const bfpair p = split_bf16(v);
        AOH[rowoffB + lane] = p.h;
        AOL[rowoffB + lane] = p.l;
    }
}

// ---------------------------------------------------------------------------
extern "C" void kernel_launch(void* const* d_in, const int* in_sizes, int n_in,
                              void* d_out, int out_size, void* d_ws, size_t ws_size,
                              hipStream_t stream)
{
    const float* x  = (const float*)d_in[0];
    const float* Wq = (const float*)d_in[1];
    const float* Wk = (const float*)d_in[2];
    const float* Wv = (const float*)d_in[3];
    const float* Wo = (const float*)d_in[4];
    float* out = (float*)d_out;

    // Workspace (4 x 16.8 MB): buf0=Q, buf1=K-dense (later AOH/AOL),
    // buf2=V, buf3=KT (holds Wq/k/v splits until step 3 overwrites).
    float* Q  = (float*)d_ws;
    float* K  = Q + (size_t)Mn * Cn;
    float* V  = K + (size_t)Mn * Cn;
    float* KT = V + (size_t)Mn * Cn;

    unsigned short* XH  = (unsigned short*)d_out;
    unsigned short* XL  = XH + (size_t)Mn * Cn;
    unsigned short* WHL = (unsigned short*)KT;
    unsigned short* AOH = (unsigned short*)K;
    unsigned short* AOL = AOH + (size_t)Mn * Cn;

    // 0) one-time hi/lo bf16 split of x and Wq/Wk/Wv
    presplit<<<dim3((unsigned)((XCHUNK + 3 * WCHUNK) / 256)), 256, 0, stream>>>(
        x, Wq, Wk, Wv, XH, XL, WHL);

    // 1) Q/K/V projections from pre-split operands
    gemm_qkv_ps<<<dim3(Cn / 128, Mn / 128, 3), 256, 0, stream>>>(
        XH, XL, WHL, Q, K, V);

    // 2) feature top-8 sparsification of Q and V, in place
    sparsify_topk<<<dim3(2 * 65536 / 4), 256, 0, stream>>>(Q, V);

    // 3) K sparsify + transpose -> KT[bh][d][t] (overwrites W splits)
    sparsify_k_t<<<dim3(32, 32), 256, 0, stream>>>(K, KT);

    // 4) sparse attention core, 2 rows/wave -> split AOH/AOL
    attn_kernel<<<dim3((Tn / 2) / NW, 32), 256, 0, stream>>>(Q, KT, V, AOH, AOL);

    // 5) output projection (pre-split A, on-the-fly W split)
    gemm_out_ps<<<dim3(Cn / 128, Mn / 128, 1), 256, 0, stream>>>(
        AOH, AOL, Wo, out);
}

// Round 11
// 785.444 us; speedup vs baseline: 1.3083x; 1.3083x over previous
//
#include <hip/hip_runtime.h>
#include <cstdint>

// Problem constants: B=2, T=2048, C=1024, H=16, D=64, TOP_K=256
// feat_keep = ceil(D*min(TOP_K,T)/T) = ceil(64*256/2048) = 8
constexpr int Tn = 2048;
constexpr int Cn = 1024;
constexpr int Mn = 4096;          // B*T
constexpr int KKEEP = 256;        // row-wise top-k
constexpr int FKEEP = 8;          // feature top-k
constexpr unsigned U_NEG_INF = 0x007FFFFFu;  // umap(-inf)

constexpr int NW     = 4;         // waves (query rows) per attn block
constexpr int NJMAX  = 32;        // max 64-col groups per row (T/64)

// Order-preserving fp32 -> uint32 map (monotonic incl. +-inf; no NaNs here).
__device__ __forceinline__ unsigned umap(float f) {
    unsigned b = __float_as_uint(f);
    return (b & 0x80000000u) ? ~b : (b | 0x80000000u);
}
__device__ __forceinline__ float uunmap(unsigned u) {
    return __uint_as_float((u & 0x80000000u) ? (u ^ 0x80000000u) : ~u);
}

// fp32 -> bf16 (RNE).
__device__ __forceinline__ unsigned short f2bf(float f) {
    unsigned u = __float_as_uint(f);
    u += 0x7FFFu + ((u >> 16) & 1u);
    return (unsigned short)(u >> 16);
}
// Split fp32 into hi+lo bf16 pair.  x ~= hi + lo, ~17-bit effective mantissa.
struct bfpair { unsigned short h, l; };
__device__ __forceinline__ bfpair split_bf16(float x) {
    bfpair r;
    r.h = f2bf(x);
    r.l = f2bf(x - __uint_as_float((unsigned)r.h << 16));
    return r;
}

// Wave-uniform broadcasts on the SALU path (NOT ds_bpermute / LDS pipe).
__device__ __forceinline__ int   rli(int v, int l)   { return __builtin_amdgcn_readlane(v, l); }
__device__ __forceinline__ float rlf(float v, int l) {
    return __int_as_float(__builtin_amdgcn_readlane(__float_as_int(v), l));
}

typedef __attribute__((ext_vector_type(8))) short          short8v;  // 8 bf16
typedef __attribute__((ext_vector_type(8))) unsigned short ushort8v;
typedef __attribute__((ext_vector_type(4))) float          f32x4;    // MFMA acc

// ---------------------------------------------------------------------------
// Pre-split pass (R18): x -> XH/XL (d_out scratch), Wq/Wk/Wv -> packed hi/lo
// (KT-buffer scratch) ONCE.  Identical f2bf math -> downstream bit-identical.
// ---------------------------------------------------------------------------
constexpr size_t XCHUNK = (size_t)Mn * Cn / 8;      // 524288 8-elem chunks
constexpr size_t WCHUNK = (size_t)Cn * Cn / 8;      // 131072 per matrix
constexpr size_t WELEMS = (size_t)Cn * Cn;          // 1048576

__device__ __forceinline__ void split8(const float* s, unsigned short* dh,
                                       unsigned short* dl, size_t base)
{
    const float4 a = *(const float4*)&s[base], b = *(const float4*)&s[base + 4];
    ushort8v h, l; bfpair p;
    p = split_bf16(a.x); h[0] = p.h; l[0] = p.l;
    p = split_bf16(a.y); h[1] = p.h; l[1] = p.l;
    p = split_bf16(a.z); h[2] = p.h; l[2] = p.l;
    p = split_bf16(a.w); h[3] = p.h; l[3] = p.l;
    p = split_bf16(b.x); h[4] = p.h; l[4] = p.l;
    p = split_bf16(b.y); h[5] = p.h; l[5] = p.l;
    p = split_bf16(b.z); h[6] = p.h; l[6] = p.l;
    p = split_bf16(b.w); h[7] = p.h; l[7] = p.l;
    *(ushort8v*)&dh[base] = h;
    *(ushort8v*)&dl[base] = l;
}

__global__ __launch_bounds__(256)
void presplit(const float* __restrict__ x,  const float* __restrict__ Wq,
              const float* __restrict__ Wk, const float* __restrict__ Wv,
              unsigned short* __restrict__ XH, unsigned short* __restrict__ XL,
              unsigned short* __restrict__ WHL)
{
    const size_t cid = (size_t)blockIdx.x * 256 + threadIdx.x;
    if (cid < XCHUNK) {
        split8(x, XH, XL, cid * 8);
    } else {
        const size_t c2 = cid - XCHUNK;
        const int    z  = (int)(c2 / WCHUNK);        // 0..2
        const size_t e  = (c2 % WCHUNK) * 8;
        const float* src = (z == 0) ? Wq : (z == 1 ? Wk : Wv);
        unsigned short* dh = WHL + (size_t)z * 2 * WELEMS;
        unsigned short* dl = dh + WELEMS;
        split8(src, dh, dl, e);
    }
}

// ---------------------------------------------------------------------------
// QKV GEMM with PRE-SPLIT operands (bit-identical MFMA sequence).
// ---------------------------------------------------------------------------
__global__ __launch_bounds__(256, 2)
void gemm_qkv_ps(const unsigned short* __restrict__ XH,
                 const unsigned short* __restrict__ XL,
                 const unsigned short* __restrict__ WHL,
                 float* __restrict__ O0, float* __restrict__ O1,
                 float* __restrict__ O2)
{
    const int z = blockIdx.z;
    const unsigned short* WH = WHL + (size_t)z * 2 * WELEMS;
    const unsigned short* WL = WH + WELEMS;
    float* O = (z == 0) ? O0 : (z == 1 ? O1 : O2);

    __shared__ unsigned short Ah[128][40], Al[128][40];
    __shared__ unsigned short Bh[128][40], Bl[128][40];

    const int tid  = threadIdx.x;
    const int lane = tid & 63;
    const int wv   = tid >> 6;
    const int wm   = wv >> 1, wn = wv & 1;
    const int fm   = lane & 15;
    const int fq   = lane >> 4;
    const int m0   = blockIdx.y * 128;
    const int n0   = blockIdx.x * 128;

    f32x4 acc[4][4] = {};

    for (int k0 = 0; k0 < Cn; k0 += 32) {
        __syncthreads();
#pragma unroll
        for (int r = 0; r < 2; ++r) {
            const int idx = tid + r * 256;
            const int row = idx >> 2, c8 = (idx & 3) * 8;
            const size_t ao = (size_t)(m0 + row) * Cn + k0 + c8;
            const size_t bo = (size_t)(n0 + row) * Cn + k0 + c8;
            *(ushort8v*)&Ah[row][c8] = *(const ushort8v*)&XH[ao];
            *(ushort8v*)&Al[row][c8] = *(const ushort8v*)&XL[ao];
            *(ushort8v*)&Bh[row][c8] = *(const ushort8v*)&WH[bo];
            *(ushort8v*)&Bl[row][c8] = *(const ushort8v*)&WL[bo];
        }
        __syncthreads();

        short8v ah[4], al[4], bh[4], bl[4];
#pragma unroll
        for (int ti = 0; ti < 4; ++ti) {
            ah[ti] = *(const short8v*)&Ah[wm * 64 + ti * 16 + fm][fq * 8];
            al[ti] = *(const short8v*)&Al[wm * 64 + ti * 16 + fm][fq * 8];
            bh[ti] = *(const short8v*)&Bh[wn * 64 + ti * 16 + fm][fq * 8];
            bl[ti] = *(const short8v*)&Bl[wn * 64 + ti * 16 + fm][fq * 8];
        }
#pragma unroll
        for (int ti = 0; ti < 4; ++ti)
#pragma unroll
            for (int tj = 0; tj < 4; ++tj) {
                acc[ti][tj] = __builtin_amdgcn_mfma_f32_16x16x32_bf16(
                    ah[ti], bh[tj], acc[ti][tj], 0, 0, 0);
                acc[ti][tj] = __builtin_amdgcn_mfma_f32_16x16x32_bf16(
                    ah[ti], bl[tj], acc[ti][tj], 0, 0, 0);
                acc[ti][tj] = __builtin_amdgcn_mfma_f32_16x16x32_bf16(
                    al[ti], bh[tj], acc[ti][tj], 0, 0, 0);
            }
    }

#pragma unroll
    for (int ti = 0; ti < 4; ++ti)
#pragma unroll
        for (int tj = 0; tj < 4; ++tj)
#pragma unroll
            for (int r = 0; r < 4; ++r) {
                const int row = m0 + wm * 64 + ti * 16 + fq * 4 + r;
                const int col = n0 + wn * 64 + tj * 16 + fm;
                O[(size_t)row * Cn + col] = acc[ti][tj][r];
            }
}

// ---------------------------------------------------------------------------
// Out-proj GEMM: A pre-split (AOH/AOL from attn), W split on the fly.
// ---------------------------------------------------------------------------
__global__ __launch_bounds__(256, 2)
void gemm_out_ps(const unsigned short* __restrict__ AH,
                 const unsigned short* __restrict__ AL,
                 const float* __restrict__ Wo, float* __restrict__ O)
{
    __shared__ unsigned short Ah[128][40], Al[128][40];
    __shared__ unsigned short Bh[128][40], Bl[128][40];

    const int tid  = threadIdx.x;
    const int lane = tid & 63;
    const int wv   = tid >> 6;
    const int wm   = wv >> 1, wn = wv & 1;
    const int fm   = lane & 15;
    const int fq   = lane >> 4;
    const int m0   = blockIdx.y * 128;
    const int n0   = blockIdx.x * 128;

    f32x4 acc[4][4] = {};

    for (int k0 = 0; k0 < Cn; k0 += 32) {
        __syncthreads();
#pragma unroll
        for (int r = 0; r < 2; ++r) {
            const int idx = tid + r * 256;
            const int row = idx >> 2, c8 = (idx & 3) * 8;
            const size_t ao = (size_t)(m0 + row) * Cn + k0 + c8;
            *(ushort8v*)&Ah[row][c8] = *(const ushort8v*)&AH[ao];
            *(ushort8v*)&Al[row][c8] = *(const ushort8v*)&AL[ao];
            {
                const float* s = &Wo[(size_t)(n0 + row) * Cn + k0 + c8];
                const float4 x0 = *(const float4*)s, x1 = *(const float4*)(s + 4);
                ushort8v h, l;
                bfpair p;
                p = split_bf16(x0.x); h[0] = p.h; l[0] = p.l;
                p = split_bf16(x0.y); h[1] = p.h; l[1] = p.l;
                p = split_bf16(x0.z); h[2] = p.h; l[2] = p.l;
                p = split_bf16(x0.w); h[3] = p.h; l[3] = p.l;
                p = split_bf16(x1.x); h[4] = p.h; l[4] = p.l;
                p = split_bf16(x1.y); h[5] = p.h; l[5] = p.l;
                p = split_bf16(x1.z); h[6] = p.h; l[6] = p.l;
                p = split_bf16(x1.w); h[7] = p.h; l[7] = p.l;
                *(ushort8v*)&Bh[row][c8] = h;
                *(ushort8v*)&Bl[row][c8] = l;
            }
        }
        __syncthreads();

        short8v ah[4], al[4], bh[4], bl[4];
#pragma unroll
        for (int ti = 0; ti < 4; ++ti) {
            ah[ti] = *(const short8v*)&Ah[wm * 64 + ti * 16 + fm][fq * 8];
            al[ti] = *(const short8v*)&Al[wm * 64 + ti * 16 + fm][fq * 8];
            bh[ti] = *(const short8v*)&Bh[wn * 64 + ti * 16 + fm][fq * 8];
            bl[ti] = *(const short8v*)&Bl[wn * 64 + ti * 16 + fm][fq * 8];
        }
#pragma unroll
        for (int ti = 0; ti < 4; ++ti)
#pragma unroll
            for (int tj = 0; tj < 4; ++tj) {
                acc[ti][tj] = __builtin_amdgcn_mfma_f32_16x16x32_bf16(
                    ah[ti], bh[tj], acc[ti][tj], 0, 0, 0);
                acc[ti][tj] = __builtin_amdgcn_mfma_f32_16x16x32_bf16(
                    ah[ti], bl[tj], acc[ti][tj], 0, 0, 0);
                acc[ti][tj] = __builtin_amdgcn_mfma_f32_16x16x32_bf16(
                    al[ti], bh[tj], acc[ti][tj], 0, 0, 0);
            }
    }

#pragma unroll
    for (int ti = 0; ti < 4; ++ti)
#pragma unroll
        for (int tj = 0; tj < 4; ++tj)
#pragma unroll
            for (int r = 0; r < 4; ++r) {
                const int row = m0 + wm * 64 + ti * 16 + fq * 4 + r;
                const int col = n0 + wn * 64 + tj * 16 + fm;
                O[(size_t)row * Cn + col] = acc[ti][tj][r];
            }
}

// ---------------------------------------------------------------------------
// Feature sparsify for Q and V (in place).
// ---------------------------------------------------------------------------
__global__ __launch_bounds__(256)
void sparsify_topk(float* __restrict__ Q, float* __restrict__ V)
{
    const int wid  = (blockIdx.x * 256 + threadIdx.x) >> 6;  // global wave id
    const int lane = threadIdx.x & 63;
    const int tensor = wid >> 16;        // 0=Q, 1=V
    const int vec    = wid & 65535;
    float* base = tensor ? V : Q;

    const size_t off = (size_t)vec * 64 + lane;
    const float v = base[off];
    const float a = fabsf(v);

    int cnt = 0;   // # strictly greater than mine
#pragma unroll
    for (int j = 0; j < 64; ++j) {
        const float aj = __shfl(a, j);
        cnt += (aj > a) ? 1 : 0;
    }
    float cand = (cnt < FKEEP) ? a : 3.402823466e38f;
#pragma unroll
    for (int o = 32; o; o >>= 1) cand = fminf(cand, __shfl_xor(cand, o));
    base[off] = (a >= cand) ? v : 0.0f;
}

// ---------------------------------------------------------------------------
// K sparsify + transpose: K[b][t][h][d] -> KT[bh][d][t].
// ---------------------------------------------------------------------------
__global__ __launch_bounds__(256)
void sparsify_k_t(const float* __restrict__ K, float* __restrict__ KT)
{
    __shared__ float tile[64][65];       // [t-row][d], pad 65

    const int tid = threadIdx.x;
    const int w = tid >> 6, lane = tid & 63;
    const int tt = blockIdx.x;           // t-tile 0..31
    const int bh = blockIdx.y;           // 0..31
    const int b = bh >> 4, h = bh & 15;
    const int t0 = tt * 64;

#pragma unroll
    for (int k = 0; k < 4; ++k) {
        const int c = tid + k * 256;     // 0..1023 float4-chunks
        const int row = c >> 4, off = (c & 15) * 4;
        const float4 v4 = *(const float4*)
            &K[(size_t)((b * Tn + t0 + row) * 16 + h) * 64 + off];
        tile[row][off + 0] = v4.x; tile[row][off + 1] = v4.y;
        tile[row][off + 2] = v4.z; tile[row][off + 3] = v4.w;
    }
    __syncthreads();

#pragma unroll 1
    for (int r = w; r < 64; r += 4) {
        const float v = tile[r][lane];
        const float a = fabsf(v);
        int cnt = 0;
#pragma unroll
        for (int j = 0; j < 64; ++j) {
            const float aj = __shfl(a, j);
            cnt += (aj > a) ? 1 : 0;
        }
        float cand = (cnt < FKEEP) ? a : 3.402823466e38f;
#pragma unroll
        for (int o = 32; o; o >>= 1) cand = fminf(cand, __shfl_xor(cand, o));
        tile[r][lane] = (a >= cand) ? v : 0.0f;
    }
    __syncthreads();

#pragma unroll
    for (int k = 0; k < 16; ++k) {
        const int d = w + k * 4;
        KT[(((size_t)bh * 64 + d) << 11) + t0 + lane] = tile[lane][d];
    }
}

// ---------------------------------------------------------------------------
// Attention core, R20 = R18 structure (proven 478us; R19's dual-row spilled
// to scratch: WRITE_SIZE 16MB->764MB -> reverted) + R19's one safe piece:
// packed uint2 (col,p) compaction.  PV reads one ds_read_b64 wave-broadcast
// per 4 cols (was 2 ds_bpermute): 64 LDS ops/row instead of 132.  Same
// stored p bits, same accumulation order -> bit-exact.
// LDS: NW*(256 hist*4B + 256 cpk*8B) = 12288 B.
// ---------------------------------------------------------------------------
__global__ __launch_bounds__(256, 4)
void attn_kernel(const float* __restrict__ Qm, const float* __restrict__ KTm,
                 const float* __restrict__ Vm,
                 unsigned short* __restrict__ AOH,
                 unsigned short* __restrict__ AOL)
{
    __shared__ unsigned hist[NW * 256];      // radix histograms (per wave)
    __shared__ uint2    cpk[NW * 256];       // compacted (col, p) (per wave)

    const int tid  = threadIdx.x;
    const int w    = tid >> 6;
    const int lane = tid & 63;
    const int bh   = blockIdx.y;             // 0..31
    const int b    = bh >> 4;
    const int h    = bh & 15;
    const int t    = blockIdx.x * NW + w;
    const size_t rowoff = ((size_t)(b * Tn + t) << 10) + (h << 6);
    const size_t kvoff  = ((size_t)(b * Tn) << 10) + (h << 6);

    // ---- sparse q row in a register; nonzero feature mask (wave-uniform) ----
    const float q0  = Qm[rowoff + lane];
    const float qsc = q0 * 0.125f;                  // fold 1/sqrt(D)
    const unsigned long long nzm = __ballot(q0 != 0.0f);
    const int nnz = __popcll(nzm);                  // wave-uniform, ==8 a.s.

    const int nj = (t >> 6) + 1;             // visible 64-col groups
    const float* ktb = KTm + ((size_t)bh << 17);    // [d][t] slice

    const bool dosel = (t >= KKEEP);         // wave-uniform
    unsigned* hrow = hist + w * 256;
    // zero my histogram row BEFORE the score pass (level-0 fused below)
    hrow[lane] = 0; hrow[64 + lane] = 0; hrow[128 + lane] = 0; hrow[192 + lane] = 0;
    __asm__ volatile("s_waitcnt lgkmcnt(0)" ::: "memory");

    // ---- score row in registers: sv[j] = umap(score of col j*64+lane) ----
    // Level-0 histogram atomics issued inline (hide under load stalls).
    unsigned sv[NJMAX];
    unsigned rowmax = 0u;
    if (nnz == 8) {
        float mq[8]; int moff[8];
        {
            unsigned long long mm = nzm;
#pragma unroll
            for (int i = 0; i < 8; ++i) {
                const int m = (int)__builtin_ctzll(mm); mm &= mm - 1;
                mq[i] = rlf(qsc, m);
                moff[i] = m << 11;
            }
        }
#pragma unroll
        for (int jq = 0; jq < NJMAX / 4; ++jq) {
            const int j0 = jq * 4;
            if (j0 >= nj) {
                sv[j0] = U_NEG_INF; sv[j0 + 1] = U_NEG_INF;
                sv[j0 + 2] = U_NEG_INF; sv[j0 + 3] = U_NEG_INF;
                continue;
            }
            const int c0 = (j0 << 6) + lane;
            if (j0 + 4 <= nj) {              // full quad: 32 loads in flight
                float s0 = 0.0f, s1 = 0.0f, s2 = 0.0f, s3 = 0.0f;
#pragma unroll
                for (int i = 0; i < 8; ++i) {
                    const float* kpi = ktb + moff[i];
                    s0 += mq[i] * kpi[c0];
                    s1 += mq[i] * kpi[c0 + 64];
                    s2 += mq[i] * kpi[c0 + 128];
                    s3 += mq[i] * kpi[c0 + 192];
                }
                const unsigned v0 = (c0       <= t) ? umap(s0) : U_NEG_INF;
                const unsigned v1 = (c0 +  64 <= t) ? umap(s1) : U_NEG_INF;
                const unsigned v2 = (c0 + 128 <= t) ? umap(s2) : U_NEG_INF;
                const unsigned v3 = (c0 + 192 <= t) ? umap(s3) : U_NEG_INF;
                sv[j0] = v0; sv[j0 + 1] = v1; sv[j0 + 2] = v2; sv[j0 + 3] = v3;
                unsigned m01 = (v0 > v1) ? v0 : v1;
                unsigned m23 = (v2 > v3) ? v2 : v3;
                m01 = (m01 > m23) ? m01 : m23;
                rowmax = (m01 > rowmax) ? m01 : rowmax;
                if (dosel) {                 // fused level-0 histogram
                    atomicAdd(&hrow[v0 >> 24], 1u);
                    atomicAdd(&hrow[v1 >> 24], 1u);
                    atomicAdd(&hrow[v2 >> 24], 1u);
                    atomicAdd(&hrow[v3 >> 24], 1u);
                }
            } else {                         // partial quad tail
#pragma unroll
                for (int k = 0; k < 4; ++k) {
                    const int j = j0 + k;
                    if (j < nj) {
                        const int col = (j << 6) + lane;
                        float s = 0.0f;
#pragma unroll
                        for (int i = 0; i < 8; ++i)
                            s += mq[i] * ktb[moff[i] + col];
                        const unsigned v = (col <= t) ? umap(s) : U_NEG_INF;
                        sv[j] = v;
                        rowmax = (v > rowmax) ? v : rowmax;
                        if (dosel) atomicAdd(&hrow[v >> 24], 1u);
                    } else sv[j] = U_NEG_INF;
                }
            }
        }
    } else {
        // generic fallback (magnitude ties -> nnz > 8): rare, wave-uniform
#pragma unroll
        for (int j = 0; j < NJMAX; ++j) {
            if (j >= nj) { sv[j] = U_NEG_INF; continue; }
            const int col = (j << 6) + lane;
            float s = 0.0f;
            unsigned long long mm = nzm;
            while (mm) {
                const int m = (int)__builtin_ctzll(mm); mm &= mm - 1;
                s += rlf(qsc, m) * ktb[((size_t)m << 11) + col];
            }
            const unsigned val = (col <= t) ? umap(s) : U_NEG_INF;
            sv[j] = val;
            rowmax = (val > rowmax) ? val : rowmax;
            if (dosel) atomicAdd(&hrow[val >> 24], 1u);
        }
    }

#pragma unroll
    for (int o = 32; o; o >>= 1) {
        const unsigned m2 = __shfl_xor(rowmax, o);
        rowmax = (m2 > rowmax) ? m2 : rowmax;
    }
    const float fm = uunmap(rowmax);         // row max (finite: col 0 <= t)

    // ---- exact kth via radix-256 select (level 0 precomputed above) ----
    unsigned cur = U_NEG_INF;                // rows t<256 keep everything
    if (dosel) {
        unsigned prefix = 0u, pmask = 0u;
        unsigned r = KKEEP;
#pragma unroll 1
        for (int level = 0; level < 4; ++level) {
            const int sh = 24 - 8 * level;
            if (level) {                     // levels 1-3: build histogram now
                hrow[lane] = 0; hrow[64 + lane] = 0;
                hrow[128 + lane] = 0; hrow[192 + lane] = 0;
                __asm__ volatile("s_waitcnt lgkmcnt(0)" ::: "memory");
#pragma unroll
                for (int j = 0; j < NJMAX; ++j) {
                    if (j < nj) {
                        const int col = (j << 6) + lane;
                        const unsigned v = sv[j];
                        if (col <= t && (v & pmask) == prefix)
                            atomicAdd(&hrow[(v >> sh) & 255u], 1u);
                    }
                }
            }
            __asm__ volatile("s_waitcnt lgkmcnt(0)" ::: "memory");
            const uint4 hv = *(const uint4*)&hrow[lane * 4];   // bins 4l..4l+3
            const unsigned ls = hv.x + hv.y + hv.z + hv.w;
            unsigned sfx = ls;                    // inclusive suffix over lanes
#pragma unroll
            for (int off = 1; off < 64; off <<= 1) {
                const unsigned tt2 = __shfl_down(sfx, off);
                if (lane + off < 64) sfx += tt2;
            }
            const unsigned excl = sfx - ls;       // lanes strictly above
            const unsigned c3 = excl + hv.w, c2 = c3 + hv.z,
                           c1 = c2 + hv.y,  c0 = c1 + hv.x;
            int bsel = -1; unsigned csel = 0, cnext = 0;
            if      (c3 >= r) { bsel = 4 * lane + 3; csel = c3; cnext = excl; }
            else if (c2 >= r) { bsel = 4 * lane + 2; csel = c2; cnext = c3; }
            else if (c1 >= r) { bsel = 4 * lane + 1; csel = c1; cnext = c2; }
            else if (c0 >= r) { bsel = 4 * lane + 0; csel = c0; cnext = c1; }
            int B = bsel;
#pragma unroll
            for (int off = 32; off; off >>= 1) {
                const int ob = __shfl_xor(B, off);
                B = (ob > B) ? ob : B;
            }
            const unsigned cB  = (unsigned)__shfl((int)csel,  B >> 2);
            const unsigned cB1 = (unsigned)__shfl((int)cnext, B >> 2);
            prefix |= (unsigned)B << sh;
            pmask  |= 255u << sh;
            if (cB == r || level == 3) { cur = prefix; break; }
            r -= cB1;                    // rank within bin B
        }
    }

    // ---- FUSED softmax + compaction: packed (col, p) uint2 into LDS ----
    uint2* cp = cpk + w * 256;           // own row only: no cross-wave hazard
    float ps = 0.0f;
    int cnt = 0; bool ovf = false;
#pragma unroll
    for (int j = 0; j < NJMAX; ++j) {
        if (j >= nj) continue;
        const int col = (j << 6) + lane;
        float pv = 0.0f;
        const unsigned uv = sv[j];
        if (col <= t && uv >= cur) pv = __expf(uunmap(uv) - fm);
        ps += pv;
        const unsigned long long m = __ballot(pv > 0.0f);
        const int c = __popcll(m);
        if (cnt + c <= 256) {
            if (pv > 0.0f) {
                const int pos = cnt + __popcll(m & ((1ull << lane) - 1ull));
                cp[pos] = make_uint2((unsigned)col, __float_as_uint(pv));
            }
        } else ovf = true;
        cnt += c;
    }
#pragma unroll
    for (int o = 32; o; o >>= 1) ps += __shfl_xor(ps, o);
    const float inv = 1.0f / ps;         // ps >= 1 (row max is kept)

    if (!ovf) {
        // zero-fill tail entries so PV needs no per-entry guard
#pragma unroll
        for (int blk = 0; blk < 4; ++blk) {
            const int idx = blk * 64 + lane;
            if (idx >= cnt) cp[idx] = make_uint2(0u, 0u);
        }
        // PV: 4 dims/lane, 4 column-subgroups.  Subgroup g = lane>>4 handles
        // list entries 4j+g via ONE ds_read_b64 broadcast (same addr across
        // the 16-lane subgroup = conflict-free); lane loads V[c][d0..d0+3].
        const int g  = lane >> 4;
        const int d0 = (lane & 15) * 4;
        float ax = 0.0f, ay = 0.0f, az = 0.0f, aw = 0.0f;
        const float* __restrict__ vb4 = Vm + kvoff + d0;
#pragma unroll
        for (int blk = 0; blk < 4; ++blk) {
            if (cnt > blk * 64) {
#pragma unroll
                for (int j = 0; j < 16; ++j) {
                    const uint2 e = cp[blk * 64 + 4 * j + g];
                    const float p = __uint_as_float(e.y);
                    const float4 v4 = *(const float4*)&vb4[(size_t)e.x * Cn];
                    ax += p * v4.x; ay += p * v4.y;
                    az += p * v4.z; aw += p * v4.w;
                }
            }
        }
        // reduce across the 4 subgroups (lanes l, l^16, l^32, l^48)
#pragma unroll
        for (int o = 16; o <= 32; o <<= 1) {
            ax += __shfl_xor(ax, o);
            ay += __shfl_xor(ay, o);
            az += __shfl_xor(az, o);
            aw += __shfl_xor(aw, o);
        }
        if (g == 0) {
            const float vx = ax * inv, vy = ay * inv,
                        vz = az * inv, vw = aw * inv;
            const bfpair px = split_bf16(vx), py = split_bf16(vy),
                         pz = split_bf16(vz), pw = split_bf16(vw);
            ushort4 hq, lq;
            hq.x = px.h; hq.y = py.h; hq.z = pz.h; hq.w = pw.h;
            lq.x = px.l; lq.y = py.l; lq.z = pz.l; lq.w = pw.l;
            *(ushort4*)&AOH[rowoff + d0] = hq;
            *(ushort4*)&AOL[rowoff + d0] = lq;
        }
    } else {
        // tie-overflow fallback (rare): while(ballot) gather from sv regs
        const float* __restrict__ vcol = Vm + kvoff + lane;
        float acc = 0.0f;
#pragma unroll
        for (int j = 0; j < NJMAX; ++j) {
            if (j >= nj) continue;
            const int col = (j << 6) + lane;
            float pv = 0.0f;
            const unsigned uv = sv[j];
            if (col <= t && uv >= cur) pv = __expf(uunmap(uv) - fm);
            unsigned long long m = __ballot(pv > 0.0f);
            const int cb = j << 6;
            while (m) {
                const int l0 = __builtin_ctzll(m); m &= m - 1;
                const float w0 = __shfl(pv, l0);
                const float v0 = vcol[(size_t)(cb + l0) * Cn];
                float w1 = 0.0f, v1 = 0.0f;
                if (m) {
                    const int l1 = __builtin_ctzll(m); m &= m - 1;
                    w1 = __shfl(pv, l1);
                    v1 = vcol[(size_t)(cb + l1) * Cn];
                }
                acc += w0 * v0;
                acc += w1 * v1;
            }
        }
        const float v = acc * inv;
        const bfpair p = split_bf16(v);
        AOH[rowoff + lane] = p.h;
        AOL[rowoff + lane] = p.l;
    }
}

// ---------------------------------------------------------------------------
extern "C" void kernel_launch(void* const* d_in, const int* in_sizes, int n_in,
                              void* d_out, int out_size, void* d_ws, size_t ws_size,
                              hipStream_t stream)
{
    const float* x  = (const float*)d_in[0];
    const float* Wq = (const float*)d_in[1];
    const float* Wk = (const float*)d_in[2];
    const float* Wv = (const float*)d_in[3];
    const float* Wo = (const float*)d_in[4];
    float* out = (float*)d_out;

    // Workspace (4 x 16.8 MB): buf0=Q, buf1=K-dense (later AOH/AOL),
    // buf2=V, buf3=KT (holds Wq/k/v splits until step 3 overwrites).
    float* Q  = (float*)d_ws;
    float* K  = Q + (size_t)Mn * Cn;
    float* V  = K + (size_t)Mn * Cn;
    float* KT = V + (size_t)Mn * Cn;

    unsigned short* XH  = (unsigned short*)d_out;
    unsigned short* XL  = XH + (size_t)Mn * Cn;
    unsigned short* WHL = (unsigned short*)KT;
    unsigned short* AOH = (unsigned short*)K;
    unsigned short* AOL = AOH + (size_t)Mn * Cn;

    // 0) one-time hi/lo bf16 split of x and Wq/Wk/Wv
    presplit<<<dim3((unsigned)((XCHUNK + 3 * WCHUNK) / 256)), 256, 0, stream>>>(
        x, Wq, Wk, Wv, XH, XL, WHL);

    // 1) Q/K/V projections from pre-split operands
    gemm_qkv_ps<<<dim3(Cn / 128, Mn / 128, 3), 256, 0, stream>>>(
        XH, XL, WHL, Q, K, V);

    // 2) feature top-8 sparsification of Q and V, in place
    sparsify_topk<<<dim3(2 * 65536 / 4), 256, 0, stream>>>(Q, V);

    // 3) K sparsify + transpose -> KT[bh][d][t] (overwrites W splits)
    sparsify_k_t<<<dim3(32, 32), 256, 0, stream>>>(K, KT);

    // 4) sparse attention core -> split AOH/AOL (overwrites K-dense)
    attn_kernel<<<dim3(Tn / NW, 32), 256, 0, stream>>>(Q, KT, V, AOH, AOL);

    // 5) output projection (pre-split A, on-the-fly W split)
    gemm_out_ps<<<dim3(Cn / 128, Mn / 128, 1), 256, 0, stream>>>(
        AOH, AOL, Wo, out);
}

// Round 12
// 775.405 us; speedup vs baseline: 1.3252x; 1.0129x over previous
//
#include <hip/hip_runtime.h>
#include <cstdint>

// Problem constants: B=2, T=2048, C=1024, H=16, D=64, TOP_K=256
// feat_keep = ceil(D*min(TOP_K,T)/T) = ceil(64*256/2048) = 8
constexpr int Tn = 2048;
constexpr int Cn = 1024;
constexpr int Mn = 4096;          // B*T
constexpr int KKEEP = 256;        // row-wise top-k
constexpr int FKEEP = 8;          // feature top-k
constexpr unsigned U_NEG_INF = 0x007FFFFFu;  // umap(-inf)

constexpr int NW     = 4;         // waves (query rows) per attn block
constexpr int NJMAX  = 32;        // max 64-col groups per row (T/64)
// Level-0 histogram: 4 replicas at stride 260 words.  260 % 32 == 4, so
// replica r's bin b sits on bank (4r + b) % 32 -> the four same-bin
// atomic chains run on FOUR DIFFERENT banks in parallel.  (R15's +256
// stride aliased all replicas to one bank -> no effect; ERRATA fixed.)
constexpr int HREP   = 260;       // words between replicas
constexpr int HWAVE  = 4 * HREP;  // 1040 words per wave

// Order-preserving fp32 -> uint32 map (monotonic incl. +-inf; no NaNs here).
__device__ __forceinline__ unsigned umap(float f) {
    unsigned b = __float_as_uint(f);
    return (b & 0x80000000u) ? ~b : (b | 0x80000000u);
}
__device__ __forceinline__ float uunmap(unsigned u) {
    return __uint_as_float((u & 0x80000000u) ? (u ^ 0x80000000u) : ~u);
}

// fp32 -> bf16 (RNE).
__device__ __forceinline__ unsigned short f2bf(float f) {
    unsigned u = __float_as_uint(f);
    u += 0x7FFFu + ((u >> 16) & 1u);
    return (unsigned short)(u >> 16);
}
// Split fp32 into hi+lo bf16 pair.  x ~= hi + lo, ~17-bit effective mantissa.
struct bfpair { unsigned short h, l; };
__device__ __forceinline__ bfpair split_bf16(float x) {
    bfpair r;
    r.h = f2bf(x);
    r.l = f2bf(x - __uint_as_float((unsigned)r.h << 16));
    return r;
}

// Wave-uniform broadcasts on the SALU path (NOT ds_bpermute / LDS pipe).
__device__ __forceinline__ int   rli(int v, int l)   { return __builtin_amdgcn_readlane(v, l); }
__device__ __forceinline__ float rlf(float v, int l) {
    return __int_as_float(__builtin_amdgcn_readlane(__float_as_int(v), l));
}

typedef __attribute__((ext_vector_type(8))) short          short8v;  // 8 bf16
typedef __attribute__((ext_vector_type(8))) unsigned short ushort8v;
typedef __attribute__((ext_vector_type(4))) float          f32x4;    // MFMA acc

// ---------------------------------------------------------------------------
// Pre-split pass (R18): x -> XH/XL (d_out scratch), Wq/Wk/Wv -> packed hi/lo
// (KT-buffer scratch) ONCE.  Identical f2bf math -> downstream bit-identical.
// ---------------------------------------------------------------------------
constexpr size_t XCHUNK = (size_t)Mn * Cn / 8;      // 524288 8-elem chunks
constexpr size_t WCHUNK = (size_t)Cn * Cn / 8;      // 131072 per matrix
constexpr size_t WELEMS = (size_t)Cn * Cn;          // 1048576

__device__ __forceinline__ void split8(const float* s, unsigned short* dh,
                                       unsigned short* dl, size_t base)
{
    const float4 a = *(const float4*)&s[base], b = *(const float4*)&s[base + 4];
    ushort8v h, l; bfpair p;
    p = split_bf16(a.x); h[0] = p.h; l[0] = p.l;
    p = split_bf16(a.y); h[1] = p.h; l[1] = p.l;
    p = split_bf16(a.z); h[2] = p.h; l[2] = p.l;
    p = split_bf16(a.w); h[3] = p.h; l[3] = p.l;
    p = split_bf16(b.x); h[4] = p.h; l[4] = p.l;
    p = split_bf16(b.y); h[5] = p.h; l[5] = p.l;
    p = split_bf16(b.z); h[6] = p.h; l[6] = p.l;
    p = split_bf16(b.w); h[7] = p.h; l[7] = p.l;
    *(ushort8v*)&dh[base] = h;
    *(ushort8v*)&dl[base] = l;
}

__global__ __launch_bounds__(256)
void presplit(const float* __restrict__ x,  const float* __restrict__ Wq,
              const float* __restrict__ Wk, const float* __restrict__ Wv,
              unsigned short* __restrict__ XH, unsigned short* __restrict__ XL,
              unsigned short* __restrict__ WHL)
{
    const size_t cid = (size_t)blockIdx.x * 256 + threadIdx.x;
    if (cid < XCHUNK) {
        split8(x, XH, XL, cid * 8);
    } else {
        const size_t c2 = cid - XCHUNK;
        const int    z  = (int)(c2 / WCHUNK);        // 0..2
        const size_t e  = (c2 % WCHUNK) * 8;
        const float* src = (z == 0) ? Wq : (z == 1 ? Wk : Wv);
        unsigned short* dh = WHL + (size_t)z * 2 * WELEMS;
        unsigned short* dl = dh + WELEMS;
        split8(src, dh, dl, e);
    }
}

// ---------------------------------------------------------------------------
// QKV GEMM with PRE-SPLIT operands (bit-identical MFMA sequence).
// ---------------------------------------------------------------------------
__global__ __launch_bounds__(256, 2)
void gemm_qkv_ps(const unsigned short* __restrict__ XH,
                 const unsigned short* __restrict__ XL,
                 const unsigned short* __restrict__ WHL,
                 float* __restrict__ O0, float* __restrict__ O1,
                 float* __restrict__ O2)
{
    const int z = blockIdx.z;
    const unsigned short* WH = WHL + (size_t)z * 2 * WELEMS;
    const unsigned short* WL = WH + WELEMS;
    float* O = (z == 0) ? O0 : (z == 1 ? O1 : O2);

    __shared__ unsigned short Ah[128][40], Al[128][40];
    __shared__ unsigned short Bh[128][40], Bl[128][40];

    const int tid  = threadIdx.x;
    const int lane = tid & 63;
    const int wv   = tid >> 6;
    const int wm   = wv >> 1, wn = wv & 1;
    const int fm   = lane & 15;
    const int fq   = lane >> 4;
    const int m0   = blockIdx.y * 128;
    const int n0   = blockIdx.x * 128;

    f32x4 acc[4][4] = {};

    for (int k0 = 0; k0 < Cn; k0 += 32) {
        __syncthreads();
#pragma unroll
        for (int r = 0; r < 2; ++r) {
            const int idx = tid + r * 256;
            const int row = idx >> 2, c8 = (idx & 3) * 8;
            const size_t ao = (size_t)(m0 + row) * Cn + k0 + c8;
            const size_t bo = (size_t)(n0 + row) * Cn + k0 + c8;
            *(ushort8v*)&Ah[row][c8] = *(const ushort8v*)&XH[ao];
            *(ushort8v*)&Al[row][c8] = *(const ushort8v*)&XL[ao];
            *(ushort8v*)&Bh[row][c8] = *(const ushort8v*)&WH[bo];
            *(ushort8v*)&Bl[row][c8] = *(const ushort8v*)&WL[bo];
        }
        __syncthreads();

        short8v ah[4], al[4], bh[4], bl[4];
#pragma unroll
        for (int ti = 0; ti < 4; ++ti) {
            ah[ti] = *(const short8v*)&Ah[wm * 64 + ti * 16 + fm][fq * 8];
            al[ti] = *(const short8v*)&Al[wm * 64 + ti * 16 + fm][fq * 8];
            bh[ti] = *(const short8v*)&Bh[wn * 64 + ti * 16 + fm][fq * 8];
            bl[ti] = *(const short8v*)&Bl[wn * 64 + ti * 16 + fm][fq * 8];
        }
#pragma unroll
        for (int ti = 0; ti < 4; ++ti)
#pragma unroll
            for (int tj = 0; tj < 4; ++tj) {
                acc[ti][tj] = __builtin_amdgcn_mfma_f32_16x16x32_bf16(
                    ah[ti], bh[tj], acc[ti][tj], 0, 0, 0);
                acc[ti][tj] = __builtin_amdgcn_mfma_f32_16x16x32_bf16(
                    ah[ti], bl[tj], acc[ti][tj], 0, 0, 0);
                acc[ti][tj] = __builtin_amdgcn_mfma_f32_16x16x32_bf16(
                    al[ti], bh[tj], acc[ti][tj], 0, 0, 0);
            }
    }

#pragma unroll
    for (int ti = 0; ti < 4; ++ti)
#pragma unroll
        for (int tj = 0; tj < 4; ++tj)
#pragma unroll
            for (int r = 0; r < 4; ++r) {
                const int row = m0 + wm * 64 + ti * 16 + fq * 4 + r;
                const int col = n0 + wn * 64 + tj * 16 + fm;
                O[(size_t)row * Cn + col] = acc[ti][tj][r];
            }
}

// ---------------------------------------------------------------------------
// Out-proj GEMM: A pre-split (AOH/AOL from attn), W split on the fly.
// ---------------------------------------------------------------------------
__global__ __launch_bounds__(256, 2)
void gemm_out_ps(const unsigned short* __restrict__ AH,
                 const unsigned short* __restrict__ AL,
                 const float* __restrict__ Wo, float* __restrict__ O)
{
    __shared__ unsigned short Ah[128][40], Al[128][40];
    __shared__ unsigned short Bh[128][40], Bl[128][40];

    const int tid  = threadIdx.x;
    const int lane = tid & 63;
    const int wv   = tid >> 6;
    const int wm   = wv >> 1, wn = wv & 1;
    const int fm   = lane & 15;
    const int fq   = lane >> 4;
    const int m0   = blockIdx.y * 128;
    const int n0   = blockIdx.x * 128;

    f32x4 acc[4][4] = {};

    for (int k0 = 0; k0 < Cn; k0 += 32) {
        __syncthreads();
#pragma unroll
        for (int r = 0; r < 2; ++r) {
            const int idx = tid + r * 256;
            const int row = idx >> 2, c8 = (idx & 3) * 8;
            const size_t ao = (size_t)(m0 + row) * Cn + k0 + c8;
            *(ushort8v*)&Ah[row][c8] = *(const ushort8v*)&AH[ao];
            *(ushort8v*)&Al[row][c8] = *(const ushort8v*)&AL[ao];
            {
                const float* s = &Wo[(size_t)(n0 + row) * Cn + k0 + c8];
                const float4 x0 = *(const float4*)s, x1 = *(const float4*)(s + 4);
                ushort8v h, l;
                bfpair p;
                p = split_bf16(x0.x); h[0] = p.h; l[0] = p.l;
                p = split_bf16(x0.y); h[1] = p.h; l[1] = p.l;
                p = split_bf16(x0.z); h[2] = p.h; l[2] = p.l;
                p = split_bf16(x0.w); h[3] = p.h; l[3] = p.l;
                p = split_bf16(x1.x); h[4] = p.h; l[4] = p.l;
                p = split_bf16(x1.y); h[5] = p.h; l[5] = p.l;
                p = split_bf16(x1.z); h[6] = p.h; l[6] = p.l;
                p = split_bf16(x1.w); h[7] = p.h; l[7] = p.l;
                *(ushort8v*)&Bh[row][c8] = h;
                *(ushort8v*)&Bl[row][c8] = l;
            }
        }
        __syncthreads();

        short8v ah[4], al[4], bh[4], bl[4];
#pragma unroll
        for (int ti = 0; ti < 4; ++ti) {
            ah[ti] = *(const short8v*)&Ah[wm * 64 + ti * 16 + fm][fq * 8];
            al[ti] = *(const short8v*)&Al[wm * 64 + ti * 16 + fm][fq * 8];
            bh[ti] = *(const short8v*)&Bh[wn * 64 + ti * 16 + fm][fq * 8];
            bl[ti] = *(const short8v*)&Bl[wn * 64 + ti * 16 + fm][fq * 8];
        }
#pragma unroll
        for (int ti = 0; ti < 4; ++ti)
#pragma unroll
            for (int tj = 0; tj < 4; ++tj) {
                acc[ti][tj] = __builtin_amdgcn_mfma_f32_16x16x32_bf16(
                    ah[ti], bh[tj], acc[ti][tj], 0, 0, 0);
                acc[ti][tj] = __builtin_amdgcn_mfma_f32_16x16x32_bf16(
                    ah[ti], bl[tj], acc[ti][tj], 0, 0, 0);
                acc[ti][tj] = __builtin_amdgcn_mfma_f32_16x16x32_bf16(
                    al[ti], bh[tj], acc[ti][tj], 0, 0, 0);
            }
    }

#pragma unroll
    for (int ti = 0; ti < 4; ++ti)
#pragma unroll
        for (int tj = 0; tj < 4; ++tj)
#pragma unroll
            for (int r = 0; r < 4; ++r) {
                const int row = m0 + wm * 64 + ti * 16 + fq * 4 + r;
                const int col = n0 + wn * 64 + tj * 16 + fm;
                O[(size_t)row * Cn + col] = acc[ti][tj][r];
            }
}

// ---------------------------------------------------------------------------
// Feature sparsify for Q and V (in place).
// ---------------------------------------------------------------------------
__global__ __launch_bounds__(256)
void sparsify_topk(float* __restrict__ Q, float* __restrict__ V)
{
    const int wid  = (blockIdx.x * 256 + threadIdx.x) >> 6;  // global wave id
    const int lane = threadIdx.x & 63;
    const int tensor = wid >> 16;        // 0=Q, 1=V
    const int vec    = wid & 65535;
    float* base = tensor ? V : Q;

    const size_t off = (size_t)vec * 64 + lane;
    const float v = base[off];
    const float a = fabsf(v);

    int cnt = 0;   // # strictly greater than mine
#pragma unroll
    for (int j = 0; j < 64; ++j) {
        const float aj = __shfl(a, j);
        cnt += (aj > a) ? 1 : 0;
    }
    float cand = (cnt < FKEEP) ? a : 3.402823466e38f;
#pragma unroll
    for (int o = 32; o; o >>= 1) cand = fminf(cand, __shfl_xor(cand, o));
    base[off] = (a >= cand) ? v : 0.0f;
}

// ---------------------------------------------------------------------------
// K sparsify + transpose: K[b][t][h][d] -> KT[bh][d][t].
// ---------------------------------------------------------------------------
__global__ __launch_bounds__(256)
void sparsify_k_t(const float* __restrict__ K, float* __restrict__ KT)
{
    __shared__ float tile[64][65];       // [t-row][d], pad 65

    const int tid = threadIdx.x;
    const int w = tid >> 6, lane = tid & 63;
    const int tt = blockIdx.x;           // t-tile 0..31
    const int bh = blockIdx.y;           // 0..31
    const int b = bh >> 4, h = bh & 15;
    const int t0 = tt * 64;

#pragma unroll
    for (int k = 0; k < 4; ++k) {
        const int c = tid + k * 256;     // 0..1023 float4-chunks
        const int row = c >> 4, off = (c & 15) * 4;
        const float4 v4 = *(const float4*)
            &K[(size_t)((b * Tn + t0 + row) * 16 + h) * 64 + off];
        tile[row][off + 0] = v4.x; tile[row][off + 1] = v4.y;
        tile[row][off + 2] = v4.z; tile[row][off + 3] = v4.w;
    }
    __syncthreads();

#pragma unroll 1
    for (int r = w; r < 64; r += 4) {
        const float v = tile[r][lane];
        const float a = fabsf(v);
        int cnt = 0;
#pragma unroll
        for (int j = 0; j < 64; ++j) {
            const float aj = __shfl(a, j);
            cnt += (aj > a) ? 1 : 0;
        }
        float cand = (cnt < FKEEP) ? a : 3.402823466e38f;
#pragma unroll
        for (int o = 32; o; o >>= 1) cand = fminf(cand, __shfl_xor(cand, o));
        tile[r][lane] = (a >= cand) ? v : 0.0f;
    }
    __syncthreads();

#pragma unroll
    for (int k = 0; k < 16; ++k) {
        const int d = w + k * 4;
        KT[(((size_t)bh * 64 + d) << 11) + t0 + lane] = tile[lane][d];
    }
}

// ---------------------------------------------------------------------------
// Attention core, R21 = R20 (best: 458us) + 4-way BANK-ROTATED level-0
// histogram replicas (stride 260 words; 260%32==4 -> replicas on banks
// +0/+4/+8/+12).  R15's failed attempt used +256 (==0 mod 32): all replicas
// aliased to one bank, so the 64-way same-address chain stayed serialized
// (conflict counter exactly unchanged).  With real bank separation the
// exponent-clustered level-0 atomics become 4 parallel 16-way chains.
// Replica sums at scan time -> selection bit-identical.  Levels 1-3 keep a
// single histogram (mantissa bins spread).
// LDS: NW*(1040 hist*4B + 256 cpk*8B) = 24832 B.
// ---------------------------------------------------------------------------
__global__ __launch_bounds__(256, 4)
void attn_kernel(const float* __restrict__ Qm, const float* __restrict__ KTm,
                 const float* __restrict__ Vm,
                 unsigned short* __restrict__ AOH,
                 unsigned short* __restrict__ AOL)
{
    __shared__ unsigned hist[NW * HWAVE];    // 4 bank-rotated replicas / wave
    __shared__ uint2    cpk[NW * 256];       // compacted (col, p) (per wave)

    const int tid  = threadIdx.x;
    const int w    = tid >> 6;
    const int lane = tid & 63;
    const int bh   = blockIdx.y;             // 0..31
    const int b    = bh >> 4;
    const int h    = bh & 15;
    const int t    = blockIdx.x * NW + w;
    const size_t rowoff = ((size_t)(b * Tn + t) << 10) + (h << 6);
    const size_t kvoff  = ((size_t)(b * Tn) << 10) + (h << 6);

    // ---- sparse q row in a register; nonzero feature mask (wave-uniform) ----
    const float q0  = Qm[rowoff + lane];
    const float qsc = q0 * 0.125f;                  // fold 1/sqrt(D)
    const unsigned long long nzm = __ballot(q0 != 0.0f);
    const int nnz = __popcll(nzm);                  // wave-uniform, ==8 a.s.

    const int nj = (t >> 6) + 1;             // visible 64-col groups
    const float* ktb = KTm + ((size_t)bh << 17);    // [d][t] slice

    const bool dosel = (t >= KKEEP);         // wave-uniform
    unsigned* hrow = hist + w * HWAVE;       // replica 0 (levels 1-3 use this)
    const int rep = (lane >> 4) * HREP;      // this lane's level-0 replica
    // zero ALL 4 replicas' bins BEFORE the score pass (level-0 fused below)
#pragma unroll
    for (int rr = 0; rr < 4; ++rr) {
        hrow[rr * HREP +   0 + lane] = 0; hrow[rr * HREP +  64 + lane] = 0;
        hrow[rr * HREP + 128 + lane] = 0; hrow[rr * HREP + 192 + lane] = 0;
    }
    __asm__ volatile("s_waitcnt lgkmcnt(0)" ::: "memory");

    // ---- score row in registers: sv[j] = umap(score of col j*64+lane) ----
    // Level-0 histogram atomics issued inline (hide under load stalls),
    // scattered across the lane's bank-rotated replica.
    unsigned sv[NJMAX];
    unsigned rowmax = 0u;
    if (nnz == 8) {
        float mq[8]; int moff[8];
        {
            unsigned long long mm = nzm;
#pragma unroll
            for (int i = 0; i < 8; ++i) {
                const int m = (int)__builtin_ctzll(mm); mm &= mm - 1;
                mq[i] = rlf(qsc, m);
                moff[i] = m << 11;
            }
        }
#pragma unroll
        for (int jq = 0; jq < NJMAX / 4; ++jq) {
            const int j0 = jq * 4;
            if (j0 >= nj) {
                sv[j0] = U_NEG_INF; sv[j0 + 1] = U_NEG_INF;
                sv[j0 + 2] = U_NEG_INF; sv[j0 + 3] = U_NEG_INF;
                continue;
            }
            const int c0 = (j0 << 6) + lane;
            if (j0 + 4 <= nj) {              // full quad: 32 loads in flight
                float s0 = 0.0f, s1 = 0.0f, s2 = 0.0f, s3 = 0.0f;
#pragma unroll
                for (int i = 0; i < 8; ++i) {
                    const float* kpi = ktb + moff[i];
                    s0 += mq[i] * kpi[c0];
                    s1 += mq[i] * kpi[c0 + 64];
                    s2 += mq[i] * kpi[c0 + 128];
                    s3 += mq[i] * kpi[c0 + 192];
                }
                const unsigned v0 = (c0       <= t) ? umap(s0) : U_NEG_INF;
                const unsigned v1 = (c0 +  64 <= t) ? umap(s1) : U_NEG_INF;
                const unsigned v2 = (c0 + 128 <= t) ? umap(s2) : U_NEG_INF;
                const unsigned v3 = (c0 + 192 <= t) ? umap(s3) : U_NEG_INF;
                sv[j0] = v0; sv[j0 + 1] = v1; sv[j0 + 2] = v2; sv[j0 + 3] = v3;
                unsigned m01 = (v0 > v1) ? v0 : v1;
                unsigned m23 = (v2 > v3) ? v2 : v3;
                m01 = (m01 > m23) ? m01 : m23;
                rowmax = (m01 > rowmax) ? m01 : rowmax;
                if (dosel) {                 // fused level-0 histogram
                    atomicAdd(&hrow[rep + (v0 >> 24)], 1u);
                    atomicAdd(&hrow[rep + (v1 >> 24)], 1u);
                    atomicAdd(&hrow[rep + (v2 >> 24)], 1u);
                    atomicAdd(&hrow[rep + (v3 >> 24)], 1u);
                }
            } else {                         // partial quad tail
#pragma unroll
                for (int k = 0; k < 4; ++k) {
                    const int j = j0 + k;
                    if (j < nj) {
                        const int col = (j << 6) + lane;
                        float s = 0.0f;
#pragma unroll
                        for (int i = 0; i < 8; ++i)
                            s += mq[i] * ktb[moff[i] + col];
                        const unsigned v = (col <= t) ? umap(s) : U_NEG_INF;
                        sv[j] = v;
                        rowmax = (v > rowmax) ? v : rowmax;
                        if (dosel) atomicAdd(&hrow[rep + (v >> 24)], 1u);
                    } else sv[j] = U_NEG_INF;
                }
            }
        }
    } else {
        // generic fallback (magnitude ties -> nnz > 8): rare, wave-uniform
#pragma unroll
        for (int j = 0; j < NJMAX; ++j) {
            if (j >= nj) { sv[j] = U_NEG_INF; continue; }
            const int col = (j << 6) + lane;
            float s = 0.0f;
            unsigned long long mm = nzm;
            while (mm) {
                const int m = (int)__builtin_ctzll(mm); mm &= mm - 1;
                s += rlf(qsc, m) * ktb[((size_t)m << 11) + col];
            }
            const unsigned val = (col <= t) ? umap(s) : U_NEG_INF;
            sv[j] = val;
            rowmax = (val > rowmax) ? val : rowmax;
            if (dosel) atomicAdd(&hrow[rep + (val >> 24)], 1u);
        }
    }

#pragma unroll
    for (int o = 32; o; o >>= 1) {
        const unsigned m2 = __shfl_xor(rowmax, o);
        rowmax = (m2 > rowmax) ? m2 : rowmax;
    }
    const float fm = uunmap(rowmax);         // row max (finite: col 0 <= t)

    // ---- exact kth via radix-256 select (level 0 precomputed above) ----
    unsigned cur = U_NEG_INF;                // rows t<256 keep everything
    if (dosel) {
        unsigned prefix = 0u, pmask = 0u;
        unsigned r = KKEEP;
#pragma unroll 1
        for (int level = 0; level < 4; ++level) {
            const int sh = 24 - 8 * level;
            if (level) {                     // levels 1-3: single histogram
                hrow[lane] = 0; hrow[64 + lane] = 0;
                hrow[128 + lane] = 0; hrow[192 + lane] = 0;
                __asm__ volatile("s_waitcnt lgkmcnt(0)" ::: "memory");
#pragma unroll
                for (int j = 0; j < NJMAX; ++j) {
                    if (j < nj) {
                        const int col = (j << 6) + lane;
                        const unsigned v = sv[j];
                        if (col <= t && (v & pmask) == prefix)
                            atomicAdd(&hrow[(v >> sh) & 255u], 1u);
                    }
                }
            }
            __asm__ volatile("s_waitcnt lgkmcnt(0)" ::: "memory");
            uint4 hv = *(const uint4*)&hrow[lane * 4];     // bins 4l..4l+3
            if (level == 0) {                // sum the other 3 replicas
#pragma unroll
                for (int rr = 1; rr < 4; ++rr) {
                    const uint4 h2 = *(const uint4*)&hrow[rr * HREP + lane * 4];
                    hv.x += h2.x; hv.y += h2.y; hv.z += h2.z; hv.w += h2.w;
                }
            }
            const unsigned ls = hv.x + hv.y + hv.z + hv.w;
            unsigned sfx = ls;                    // inclusive suffix over lanes
#pragma unroll
            for (int off = 1; off < 64; off <<= 1) {
                const unsigned tt2 = __shfl_down(sfx, off);
                if (lane + off < 64) sfx += tt2;
            }
            const unsigned excl = sfx - ls;       // lanes strictly above
            const unsigned c3 = excl + hv.w, c2 = c3 + hv.z,
                           c1 = c2 + hv.y,  c0 = c1 + hv.x;
            int bsel = -1; unsigned csel = 0, cnext = 0;
            if      (c3 >= r) { bsel = 4 * lane + 3; csel = c3; cnext = excl; }
            else if (c2 >= r) { bsel = 4 * lane + 2; csel = c2; cnext = c3; }
            else if (c1 >= r) { bsel = 4 * lane + 1; csel = c1; cnext = c2; }
            else if (c0 >= r) { bsel = 4 * lane + 0; csel = c0; cnext = c1; }
            int B = bsel;
#pragma unroll
            for (int off = 32; off; off >>= 1) {
                const int ob = __shfl_xor(B, off);
                B = (ob > B) ? ob : B;
            }
            const unsigned cB  = (unsigned)__shfl((int)csel,  B >> 2);
            const unsigned cB1 = (unsigned)__shfl((int)cnext, B >> 2);
            prefix |= (unsigned)B << sh;
            pmask  |= 255u << sh;
            if (cB == r || level == 3) { cur = prefix; break; }
            r -= cB1;                    // rank within bin B
        }
    }

    // ---- FUSED softmax + compaction: packed (col, p) uint2 into LDS ----
    uint2* cp = cpk + w * 256;           // own row only: no cross-wave hazard
    float ps = 0.0f;
    int cnt = 0; bool ovf = false;
#pragma unroll
    for (int j = 0; j < NJMAX; ++j) {
        if (j >= nj) continue;
        const int col = (j << 6) + lane;
        float pv = 0.0f;
        const unsigned uv = sv[j];
        if (col <= t && uv >= cur) pv = __expf(uunmap(uv) - fm);
        ps += pv;
        const unsigned long long m = __ballot(pv > 0.0f);
        const int c = __popcll(m);
        if (cnt + c <= 256) {
            if (pv > 0.0f) {
                const int pos = cnt + __popcll(m & ((1ull << lane) - 1ull));
                cp[pos] = make_uint2((unsigned)col, __float_as_uint(pv));
            }
        } else ovf = true;
        cnt += c;
    }
#pragma unroll
    for (int o = 32; o; o >>= 1) ps += __shfl_xor(ps, o);
    const float inv = 1.0f / ps;         // ps >= 1 (row max is kept)

    if (!ovf) {
        // zero-fill tail entries so PV needs no per-entry guard
#pragma unroll
        for (int blk = 0; blk < 4; ++blk) {
            const int idx = blk * 64 + lane;
            if (idx >= cnt) cp[idx] = make_uint2(0u, 0u);
        }
        // PV: 4 dims/lane, 4 column-subgroups.  Subgroup g = lane>>4 handles
        // list entries 4j+g via ONE ds_read_b64 broadcast (same addr across
        // the 16-lane subgroup = conflict-free); lane loads V[c][d0..d0+3].
        const int g  = lane >> 4;
        const int d0 = (lane & 15) * 4;
        float ax = 0.0f, ay = 0.0f, az = 0.0f, aw = 0.0f;
        const float* __restrict__ vb4 = Vm + kvoff + d0;
#pragma unroll
        for (int blk = 0; blk < 4; ++blk) {
            if (cnt > blk * 64) {
#pragma unroll
                for (int j = 0; j < 16; ++j) {
                    const uint2 e = cp[blk * 64 + 4 * j + g];
                    const float p = __uint_as_float(e.y);
                    const float4 v4 = *(const float4*)&vb4[(size_t)e.x * Cn];
                    ax += p * v4.x; ay += p * v4.y;
                    az += p * v4.z; aw += p * v4.w;
                }
            }
        }
        // reduce across the 4 subgroups (lanes l, l^16, l^32, l^48)
#pragma unroll
        for (int o = 16; o <= 32; o <<= 1) {
            ax += __shfl_xor(ax, o);
            ay += __shfl_xor(ay, o);
            az += __shfl_xor(az, o);
            aw += __shfl_xor(aw, o);
        }
        if (g == 0) {
            const float vx = ax * inv, vy = ay * inv,
                        vz = az * inv, vw = aw * inv;
            const bfpair px = split_bf16(vx), py = split_bf16(vy),
                         pz = split_bf16(vz), pw = split_bf16(vw);
            ushort4 hq, lq;
            hq.x = px.h; hq.y = py.h; hq.z = pz.h; hq.w = pw.h;
            lq.x = px.l; lq.y = py.l; lq.z = pz.l; lq.w = pw.l;
            *(ushort4*)&AOH[rowoff + d0] = hq;
            *(ushort4*)&AOL[rowoff + d0] = lq;
        }
    } else {
        // tie-overflow fallback (rare): while(ballot) gather from sv regs
        const float* __restrict__ vcol = Vm + kvoff + lane;
        float acc = 0.0f;
#pragma unroll
        for (int j = 0; j < NJMAX; ++j) {
            if (j >= nj) continue;
            const int col = (j << 6) + lane;
            float pv = 0.0f;
            const unsigned uv = sv[j];
            if (col <= t && uv >= cur) pv = __expf(uunmap(uv) - fm);
            unsigned long long m = __ballot(pv > 0.0f);
            const int cb = j << 6;
            while (m) {
                const int l0 = __builtin_ctzll(m); m &= m - 1;
                const float w0 = __shfl(pv, l0);
                const float v0 = vcol[(size_t)(cb + l0) * Cn];
                float w1 = 0.0f, v1 = 0.0f;
                if (m) {
                    const int l1 = __builtin_ctzll(m); m &= m - 1;
                    w1 = __shfl(pv, l1);
                    v1 = vcol[(size_t)(cb + l1) * Cn];
                }
                acc += w0 * v0;
                acc += w1 * v1;
            }
        }
        const float v = acc * inv;
        const bfpair p = split_bf16(v);
        AOH[rowoff + lane] = p.h;
        AOL[rowoff + lane] = p.l;
    }
}

// ---------------------------------------------------------------------------
extern "C" void kernel_launch(void* const* d_in, const int* in_sizes, int n_in,
                              void* d_out, int out_size, void* d_ws, size_t ws_size,
                              hipStream_t stream)
{
    const float* x  = (const float*)d_in[0];
    const float* Wq = (const float*)d_in[1];
    const float* Wk = (const float*)d_in[2];
    const float* Wv = (const float*)d_in[3];
    const float* Wo = (const float*)d_in[4];
    float* out = (float*)d_out;

    // Workspace (4 x 16.8 MB): buf0=Q, buf1=K-dense (later AOH/AOL),
    // buf2=V, buf3=KT (holds Wq/k/v splits until step 3 overwrites).
    float* Q  = (float*)d_ws;
    float* K  = Q + (size_t)Mn * Cn;
    float* V  = K + (size_t)Mn * Cn;
    float* KT = V + (size_t)Mn * Cn;

    unsigned short* XH  = (unsigned short*)d_out;
    unsigned short* XL  = XH + (size_t)Mn * Cn;
    unsigned short* WHL = (unsigned short*)KT;
    unsigned short* AOH = (unsigned short*)K;
    unsigned short* AOL = AOH + (size_t)Mn * Cn;

    // 0) one-time hi/lo bf16 split of x and Wq/Wk/Wv
    presplit<<<dim3((unsigned)((XCHUNK + 3 * WCHUNK) / 256)), 256, 0, stream>>>(
        x, Wq, Wk, Wv, XH, XL, WHL);

    // 1) Q/K/V projections from pre-split operands
    gemm_qkv_ps<<<dim3(Cn / 128, Mn / 128, 3), 256, 0, stream>>>(
        XH, XL, WHL, Q, K, V);

    // 2) feature top-8 sparsification of Q and V, in place
    sparsify_topk<<<dim3(2 * 65536 / 4), 256, 0, stream>>>(Q, V);

    // 3) K sparsify + transpose -> KT[bh][d][t] (overwrites W splits)
    sparsify_k_t<<<dim3(32, 32), 256, 0, stream>>>(K, KT);

    // 4) sparse attention core -> split AOH/AOL (overwrites K-dense)
    attn_kernel<<<dim3(Tn / NW, 32), 256, 0, stream>>>(Q, KT, V, AOH, AOL);

    // 5) output projection (pre-split A, on-the-fly W split)
    gemm_out_ps<<<dim3(Cn / 128, Mn / 128, 1), 256, 0, stream>>>(
        AOH, AOL, Wo, out);
}

// Round 13
// 769.466 us; speedup vs baseline: 1.3354x; 1.0077x over previous
//
#include <hip/hip_runtime.h>
#include <cstdint>

// Problem constants: B=2, T=2048, C=1024, H=16, D=64, TOP_K=256
// feat_keep = ceil(D*min(TOP_K,T)/T) = ceil(64*256/2048) = 8
constexpr int Tn = 2048;
constexpr int Cn = 1024;
constexpr int Mn = 4096;          // B*T
constexpr int KKEEP = 256;        // row-wise top-k
constexpr int FKEEP = 8;          // feature top-k
constexpr unsigned U_NEG_INF = 0x007FFFFFu;  // umap(-inf)

constexpr int NW     = 4;         // waves (query rows) per attn block
constexpr int NJMAX  = 32;        // max 64-col groups per row (T/64)
// Level-0 histogram: 4 replicas at stride 260 words (260%32==4 -> replicas
// on banks +0/+4/+8/+12; same-bin atomics run on 4 banks in parallel).
constexpr int HREP   = 260;       // words between replicas
constexpr int HWAVE  = 4 * HREP;  // 1040 words per wave

// Order-preserving fp32 -> uint32 map (monotonic incl. +-inf; no NaNs here).
__device__ __forceinline__ unsigned umap(float f) {
    unsigned b = __float_as_uint(f);
    return (b & 0x80000000u) ? ~b : (b | 0x80000000u);
}
__device__ __forceinline__ float uunmap(unsigned u) {
    return __uint_as_float((u & 0x80000000u) ? (u ^ 0x80000000u) : ~u);
}

// fp32 -> bf16 (RNE).
__device__ __forceinline__ unsigned short f2bf(float f) {
    unsigned u = __float_as_uint(f);
    u += 0x7FFFu + ((u >> 16) & 1u);
    return (unsigned short)(u >> 16);
}
// Split fp32 into hi+lo bf16 pair.  x ~= hi + lo, ~17-bit effective mantissa.
struct bfpair { unsigned short h, l; };
__device__ __forceinline__ bfpair split_bf16(float x) {
    bfpair r;
    r.h = f2bf(x);
    r.l = f2bf(x - __uint_as_float((unsigned)r.h << 16));
    return r;
}

// Wave-uniform broadcasts on the SALU path (NOT ds_bpermute / LDS pipe).
__device__ __forceinline__ int   rli(int v, int l)   { return __builtin_amdgcn_readlane(v, l); }
__device__ __forceinline__ float rlf(float v, int l) {
    return __int_as_float(__builtin_amdgcn_readlane(__float_as_int(v), l));
}

// Async global->LDS, 16B per lane: lane l writes ldsbase + l*16 (linear).
__device__ __forceinline__ void glds16(const void* g, void* l) {
    __builtin_amdgcn_global_load_lds(
        (const __attribute__((address_space(1))) void*)g,
        (__attribute__((address_space(3))) void*)l, 16, 0, 0);
}

typedef __attribute__((ext_vector_type(8))) short          short8v;  // 8 bf16
typedef __attribute__((ext_vector_type(8))) unsigned short ushort8v;
typedef __attribute__((ext_vector_type(4))) float          f32x4;    // MFMA acc

// ---------------------------------------------------------------------------
// Pre-split pass (R18): x -> XH/XL (d_out scratch), Wq/Wk/Wv -> packed hi/lo
// (KT-buffer scratch) ONCE.  Identical f2bf math -> downstream bit-identical.
// ---------------------------------------------------------------------------
constexpr size_t XCHUNK = (size_t)Mn * Cn / 8;      // 524288 8-elem chunks
constexpr size_t WCHUNK = (size_t)Cn * Cn / 8;      // 131072 per matrix
constexpr size_t WELEMS = (size_t)Cn * Cn;          // 1048576

__device__ __forceinline__ void split8(const float* s, unsigned short* dh,
                                       unsigned short* dl, size_t base)
{
    const float4 a = *(const float4*)&s[base], b = *(const float4*)&s[base + 4];
    ushort8v h, l; bfpair p;
    p = split_bf16(a.x); h[0] = p.h; l[0] = p.l;
    p = split_bf16(a.y); h[1] = p.h; l[1] = p.l;
    p = split_bf16(a.z); h[2] = p.h; l[2] = p.l;
    p = split_bf16(a.w); h[3] = p.h; l[3] = p.l;
    p = split_bf16(b.x); h[4] = p.h; l[4] = p.l;
    p = split_bf16(b.y); h[5] = p.h; l[5] = p.l;
    p = split_bf16(b.z); h[6] = p.h; l[6] = p.l;
    p = split_bf16(b.w); h[7] = p.h; l[7] = p.l;
    *(ushort8v*)&dh[base] = h;
    *(ushort8v*)&dl[base] = l;
}

__global__ __launch_bounds__(256)
void presplit(const float* __restrict__ x,  const float* __restrict__ Wq,
              const float* __restrict__ Wk, const float* __restrict__ Wv,
              unsigned short* __restrict__ XH, unsigned short* __restrict__ XL,
              unsigned short* __restrict__ WHL)
{
    const size_t cid = (size_t)blockIdx.x * 256 + threadIdx.x;
    if (cid < XCHUNK) {
        split8(x, XH, XL, cid * 8);
    } else {
        const size_t c2 = cid - XCHUNK;
        const int    z  = (int)(c2 / WCHUNK);        // 0..2
        const size_t e  = (c2 % WCHUNK) * 8;
        const float* src = (z == 0) ? Wq : (z == 1 ? Wk : Wv);
        unsigned short* dh = WHL + (size_t)z * 2 * WELEMS;
        unsigned short* dl = dh + WELEMS;
        split8(src, dh, dl, e);
    }
}

// ---------------------------------------------------------------------------
// QKV GEMM, R22: pre-split operands staged via async global_load_lds
// (width=16) into UNPADDED [128][32] LDS (linear dest required by glds —
// guide m97: 517->874 TF from this one change; the 8-way fragment-read
// conflicts at 64B rows are the m98-measured tradeoff, net win).
// MFMA sequence identical -> outputs bit-identical.
// ---------------------------------------------------------------------------
__global__ __launch_bounds__(256, 2)
void gemm_qkv_ps(const unsigned short* __restrict__ XH,
                 const unsigned short* __restrict__ XL,
                 const unsigned short* __restrict__ WHL,
                 float* __restrict__ O0, float* __restrict__ O1,
                 float* __restrict__ O2)
{
    const int z = blockIdx.z;
    const unsigned short* WH = WHL + (size_t)z * 2 * WELEMS;
    const unsigned short* WL = WH + WELEMS;
    float* O = (z == 0) ? O0 : (z == 1 ? O1 : O2);

    __shared__ unsigned short Ah[128][32], Al[128][32];   // 4 x 8 KB
    __shared__ unsigned short Bh[128][32], Bl[128][32];

    const int tid  = threadIdx.x;
    const int lane = tid & 63;
    const int wv   = tid >> 6;
    const int wm   = wv >> 1, wn = wv & 1;
    const int fm   = lane & 15;
    const int fq   = lane >> 4;
    const int m0   = blockIdx.y * 128;
    const int n0   = blockIdx.x * 128;

    // per-lane glds source coords: lane l covers row slab_base + l/4,
    // elems (l%4)*8 .. +8 (16B) — matches glds' linear dest lane mapping.
    const int srow = lane >> 2;
    const int se0  = (lane & 3) * 8;

    f32x4 acc[4][4] = {};

    for (int k0 = 0; k0 < Cn; k0 += 32) {
        __syncthreads();
        // wave wv stages rows [32wv, 32wv+32) of all 4 buffers:
        // 2 slabs x 4 buffers = 8 glds calls per wave per K-step.
#pragma unroll
        for (int c = 0; c < 2; ++c) {
            const int rb  = wv * 32 + c * 16;        // slab row base
            const int row = rb + srow;
            const size_t ao = (size_t)(m0 + row) * Cn + k0 + se0;
            const size_t bo = (size_t)(n0 + row) * Cn + k0 + se0;
            glds16(XH + ao, &Ah[rb][0]);
            glds16(XL + ao, &Al[rb][0]);
            glds16(WH + bo, &Bh[rb][0]);
            glds16(WL + bo, &Bl[rb][0]);
        }
        __syncthreads();   // vmcnt(0) drain: all glds landed

        short8v ah[4], al[4], bh[4], bl[4];
#pragma unroll
        for (int ti = 0; ti < 4; ++ti) {
            ah[ti] = *(const short8v*)&Ah[wm * 64 + ti * 16 + fm][fq * 8];
            al[ti] = *(const short8v*)&Al[wm * 64 + ti * 16 + fm][fq * 8];
            bh[ti] = *(const short8v*)&Bh[wn * 64 + ti * 16 + fm][fq * 8];
            bl[ti] = *(const short8v*)&Bl[wn * 64 + ti * 16 + fm][fq * 8];
        }
#pragma unroll
        for (int ti = 0; ti < 4; ++ti)
#pragma unroll
            for (int tj = 0; tj < 4; ++tj) {
                acc[ti][tj] = __builtin_amdgcn_mfma_f32_16x16x32_bf16(
                    ah[ti], bh[tj], acc[ti][tj], 0, 0, 0);
                acc[ti][tj] = __builtin_amdgcn_mfma_f32_16x16x32_bf16(
                    ah[ti], bl[tj], acc[ti][tj], 0, 0, 0);
                acc[ti][tj] = __builtin_amdgcn_mfma_f32_16x16x32_bf16(
                    al[ti], bh[tj], acc[ti][tj], 0, 0, 0);
            }
    }

#pragma unroll
    for (int ti = 0; ti < 4; ++ti)
#pragma unroll
        for (int tj = 0; tj < 4; ++tj)
#pragma unroll
            for (int r = 0; r < 4; ++r) {
                const int row = m0 + wm * 64 + ti * 16 + fq * 4 + r;
                const int col = n0 + wn * 64 + tj * 16 + fm;
                O[(size_t)row * Cn + col] = acc[ti][tj][r];
            }
}

// ---------------------------------------------------------------------------
// Out-proj GEMM, R22: A (pre-split AOH/AOL) via glds into unpadded LDS;
// Wo split on the fly into padded LDS (unchanged).  Bit-identical math.
// ---------------------------------------------------------------------------
__global__ __launch_bounds__(256, 2)
void gemm_out_ps(const unsigned short* __restrict__ AH,
                 const unsigned short* __restrict__ AL,
                 const float* __restrict__ Wo, float* __restrict__ O)
{
    __shared__ unsigned short Ah[128][32], Al[128][32];   // glds, linear
    __shared__ unsigned short Bh[128][40], Bl[128][40];   // VALU-split, padded

    const int tid  = threadIdx.x;
    const int lane = tid & 63;
    const int wv   = tid >> 6;
    const int wm   = wv >> 1, wn = wv & 1;
    const int fm   = lane & 15;
    const int fq   = lane >> 4;
    const int m0   = blockIdx.y * 128;
    const int n0   = blockIdx.x * 128;

    const int srow = lane >> 2;
    const int se0  = (lane & 3) * 8;

    f32x4 acc[4][4] = {};

    for (int k0 = 0; k0 < Cn; k0 += 32) {
        __syncthreads();
        // A operand: async glds (4 calls/wave)
#pragma unroll
        for (int c = 0; c < 2; ++c) {
            const int rb  = wv * 32 + c * 16;
            const int row = rb + srow;
            const size_t ao = (size_t)(m0 + row) * Cn + k0 + se0;
            glds16(AH + ao, &Ah[rb][0]);
            glds16(AL + ao, &Al[rb][0]);
        }
        // B operand: split Wo on the fly (2 chunks/thread)
#pragma unroll
        for (int r = 0; r < 2; ++r) {
            const int idx = tid + r * 256;
            const int row = idx >> 2, c8 = (idx & 3) * 8;
            const float* s = &Wo[(size_t)(n0 + row) * Cn + k0 + c8];
            const float4 x0 = *(const float4*)s, x1 = *(const float4*)(s + 4);
            ushort8v h, l;
            bfpair p;
            p = split_bf16(x0.x); h[0] = p.h; l[0] = p.l;
            p = split_bf16(x0.y); h[1] = p.h; l[1] = p.l;
            p = split_bf16(x0.z); h[2] = p.h; l[2] = p.l;
            p = split_bf16(x0.w); h[3] = p.h; l[3] = p.l;
            p = split_bf16(x1.x); h[4] = p.h; l[4] = p.l;
            p = split_bf16(x1.y); h[5] = p.h; l[5] = p.l;
            p = split_bf16(x1.z); h[6] = p.h; l[6] = p.l;
            p = split_bf16(x1.w); h[7] = p.h; l[7] = p.l;
            *(ushort8v*)&Bh[row][c8] = h;
            *(ushort8v*)&Bl[row][c8] = l;
        }
        __syncthreads();

        short8v ah[4], al[4], bh[4], bl[4];
#pragma unroll
        for (int ti = 0; ti < 4; ++ti) {
            ah[ti] = *(const short8v*)&Ah[wm * 64 + ti * 16 + fm][fq * 8];
            al[ti] = *(const short8v*)&Al[wm * 64 + ti * 16 + fm][fq * 8];
            bh[ti] = *(const short8v*)&Bh[wn * 64 + ti * 16 + fm][fq * 8];
            bl[ti] = *(const short8v*)&Bl[wn * 64 + ti * 16 + fm][fq * 8];
        }
#pragma unroll
        for (int ti = 0; ti < 4; ++ti)
#pragma unroll
            for (int tj = 0; tj < 4; ++tj) {
                acc[ti][tj] = __builtin_amdgcn_mfma_f32_16x16x32_bf16(
                    ah[ti], bh[tj], acc[ti][tj], 0, 0, 0);
                acc[ti][tj] = __builtin_amdgcn_mfma_f32_16x16x32_bf16(
                    ah[ti], bl[tj], acc[ti][tj], 0, 0, 0);
                acc[ti][tj] = __builtin_amdgcn_mfma_f32_16x16x32_bf16(
                    al[ti], bh[tj], acc[ti][tj], 0, 0, 0);
            }
    }

#pragma unroll
    for (int ti = 0; ti < 4; ++ti)
#pragma unroll
        for (int tj = 0; tj < 4; ++tj)
#pragma unroll
            for (int r = 0; r < 4; ++r) {
                const int row = m0 + wm * 64 + ti * 16 + fq * 4 + r;
                const int col = n0 + wn * 64 + tj * 16 + fm;
                O[(size_t)row * Cn + col] = acc[ti][tj][r];
            }
}

// ---------------------------------------------------------------------------
// Feature sparsify for Q and V (in place).
// ---------------------------------------------------------------------------
__global__ __launch_bounds__(256)
void sparsify_topk(float* __restrict__ Q, float* __restrict__ V)
{
    const int wid  = (blockIdx.x * 256 + threadIdx.x) >> 6;  // global wave id
    const int lane = threadIdx.x & 63;
    const int tensor = wid >> 16;        // 0=Q, 1=V
    const int vec    = wid & 65535;
    float* base = tensor ? V : Q;

    const size_t off = (size_t)vec * 64 + lane;
    const float v = base[off];
    const float a = fabsf(v);

    int cnt = 0;   // # strictly greater than mine
#pragma unroll
    for (int j = 0; j < 64; ++j) {
        const float aj = __shfl(a, j);
        cnt += (aj > a) ? 1 : 0;
    }
    float cand = (cnt < FKEEP) ? a : 3.402823466e38f;
#pragma unroll
    for (int o = 32; o; o >>= 1) cand = fminf(cand, __shfl_xor(cand, o));
    base[off] = (a >= cand) ? v : 0.0f;
}

// ---------------------------------------------------------------------------
// K sparsify + transpose: K[b][t][h][d] -> KT[bh][d][t].
// ---------------------------------------------------------------------------
__global__ __launch_bounds__(256)
void sparsify_k_t(const float* __restrict__ K, float* __restrict__ KT)
{
    __shared__ float tile[64][65];       // [t-row][d], pad 65

    const int tid = threadIdx.x;
    const int w = tid >> 6, lane = tid & 63;
    const int tt = blockIdx.x;           // t-tile 0..31
    const int bh = blockIdx.y;           // 0..31
    const int b = bh >> 4, h = bh & 15;
    const int t0 = tt * 64;

#pragma unroll
    for (int k = 0; k < 4; ++k) {
        const int c = tid + k * 256;     // 0..1023 float4-chunks
        const int row = c >> 4, off = (c & 15) * 4;
        const float4 v4 = *(const float4*)
            &K[(size_t)((b * Tn + t0 + row) * 16 + h) * 64 + off];
        tile[row][off + 0] = v4.x; tile[row][off + 1] = v4.y;
        tile[row][off + 2] = v4.z; tile[row][off + 3] = v4.w;
    }
    __syncthreads();

#pragma unroll 1
    for (int r = w; r < 64; r += 4) {
        const float v = tile[r][lane];
        const float a = fabsf(v);
        int cnt = 0;
#pragma unroll
        for (int j = 0; j < 64; ++j) {
            const float aj = __shfl(a, j);
            cnt += (aj > a) ? 1 : 0;
        }
        float cand = (cnt < FKEEP) ? a : 3.402823466e38f;
#pragma unroll
        for (int o = 32; o; o >>= 1) cand = fminf(cand, __shfl_xor(cand, o));
        tile[r][lane] = (a >= cand) ? v : 0.0f;
    }
    __syncthreads();

#pragma unroll
    for (int k = 0; k < 16; ++k) {
        const int d = w + k * 4;
        KT[(((size_t)bh * 64 + d) << 11) + t0 + lane] = tile[lane][d];
    }
}

// ---------------------------------------------------------------------------
// Attention core, unchanged from R21 (best: 453us; bank-rotated level-0
// histogram replicas + packed uint2 compaction + fused level-0 atomics).
// ---------------------------------------------------------------------------
__global__ __launch_bounds__(256, 4)
void attn_kernel(const float* __restrict__ Qm, const float* __restrict__ KTm,
                 const float* __restrict__ Vm,
                 unsigned short* __restrict__ AOH,
                 unsigned short* __restrict__ AOL)
{
    __shared__ unsigned hist[NW * HWAVE];    // 4 bank-rotated replicas / wave
    __shared__ uint2    cpk[NW * 256];       // compacted (col, p) (per wave)

    const int tid  = threadIdx.x;
    const int w    = tid >> 6;
    const int lane = tid & 63;
    const int bh   = blockIdx.y;             // 0..31
    const int b    = bh >> 4;
    const int h    = bh & 15;
    const int t    = blockIdx.x * NW + w;
    const size_t rowoff = ((size_t)(b * Tn + t) << 10) + (h << 6);
    const size_t kvoff  = ((size_t)(b * Tn) << 10) + (h << 6);

    // ---- sparse q row in a register; nonzero feature mask (wave-uniform) ----
    const float q0  = Qm[rowoff + lane];
    const float qsc = q0 * 0.125f;                  // fold 1/sqrt(D)
    const unsigned long long nzm = __ballot(q0 != 0.0f);
    const int nnz = __popcll(nzm);                  // wave-uniform, ==8 a.s.

    const int nj = (t >> 6) + 1;             // visible 64-col groups
    const float* ktb = KTm + ((size_t)bh << 17);    // [d][t] slice

    const bool dosel = (t >= KKEEP);         // wave-uniform
    unsigned* hrow = hist + w * HWAVE;       // replica 0 (levels 1-3 use this)
    const int rep = (lane >> 4) * HREP;      // this lane's level-0 replica
    // zero ALL 4 replicas' bins BEFORE the score pass (level-0 fused below)
#pragma unroll
    for (int rr = 0; rr < 4; ++rr) {
        hrow[rr * HREP +   0 + lane] = 0; hrow[rr * HREP +  64 + lane] = 0;
        hrow[rr * HREP + 128 + lane] = 0; hrow[rr * HREP + 192 + lane] = 0;
    }
    __asm__ volatile("s_waitcnt lgkmcnt(0)" ::: "memory");

    // ---- score row in registers: sv[j] = umap(score of col j*64+lane) ----
    // Level-0 histogram atomics issued inline (hide under load stalls),
    // scattered across the lane's bank-rotated replica.
    unsigned sv[NJMAX];
    unsigned rowmax = 0u;
    if (nnz == 8) {
        float mq[8]; int moff[8];
        {
            unsigned long long mm = nzm;
#pragma unroll
            for (int i = 0; i < 8; ++i) {
                const int m = (int)__builtin_ctzll(mm); mm &= mm - 1;
                mq[i] = rlf(qsc, m);
                moff[i] = m << 11;
            }
        }
#pragma unroll
        for (int jq = 0; jq < NJMAX / 4; ++jq) {
            const int j0 = jq * 4;
            if (j0 >= nj) {
                sv[j0] = U_NEG_INF; sv[j0 + 1] = U_NEG_INF;
                sv[j0 + 2] = U_NEG_INF; sv[j0 + 3] = U_NEG_INF;
                continue;
            }
            const int c0 = (j0 << 6) + lane;
            if (j0 + 4 <= nj) {              // full quad: 32 loads in flight
                float s0 = 0.0f, s1 = 0.0f, s2 = 0.0f, s3 = 0.0f;
#pragma unroll
                for (int i = 0; i < 8; ++i) {
                    const float* kpi = ktb + moff[i];
                    s0 += mq[i] * kpi[c0];
                    s1 += mq[i] * kpi[c0 + 64];
                    s2 += mq[i] * kpi[c0 + 128];
                    s3 += mq[i] * kpi[c0 + 192];
                }
                const unsigned v0 = (c0       <= t) ? umap(s0) : U_NEG_INF;
                const unsigned v1 = (c0 +  64 <= t) ? umap(s1) : U_NEG_INF;
                const unsigned v2 = (c0 + 128 <= t) ? umap(s2) : U_NEG_INF;
                const unsigned v3 = (c0 + 192 <= t) ? umap(s3) : U_NEG_INF;
                sv[j0] = v0; sv[j0 + 1] = v1; sv[j0 + 2] = v2; sv[j0 + 3] = v3;
                unsigned m01 = (v0 > v1) ? v0 : v1;
                unsigned m23 = (v2 > v3) ? v2 : v3;
                m01 = (m01 > m23) ? m01 : m23;
                rowmax = (m01 > rowmax) ? m01 : rowmax;
                if (dosel) {                 // fused level-0 histogram
                    atomicAdd(&hrow[rep + (v0 >> 24)], 1u);
                    atomicAdd(&hrow[rep + (v1 >> 24)], 1u);
                    atomicAdd(&hrow[rep + (v2 >> 24)], 1u);
                    atomicAdd(&hrow[rep + (v3 >> 24)], 1u);
                }
            } else {                         // partial quad tail
#pragma unroll
                for (int k = 0; k < 4; ++k) {
                    const int j = j0 + k;
                    if (j < nj) {
                        const int col = (j << 6) + lane;
                        float s = 0.0f;
#pragma unroll
                        for (int i = 0; i < 8; ++i)
                            s += mq[i] * ktb[moff[i] + col];
                        const unsigned v = (col <= t) ? umap(s) : U_NEG_INF;
                        sv[j] = v;
                        rowmax = (v > rowmax) ? v : rowmax;
                        if (dosel) atomicAdd(&hrow[rep + (v >> 24)], 1u);
                    } else sv[j] = U_NEG_INF;
                }
            }
        }
    } else {
        // generic fallback (magnitude ties -> nnz > 8): rare, wave-uniform
#pragma unroll
        for (int j = 0; j < NJMAX; ++j) {
            if (j >= nj) { sv[j] = U_NEG_INF; continue; }
            const int col = (j << 6) + lane;
            float s = 0.0f;
            unsigned long long mm = nzm;
            while (mm) {
                const int m = (int)__builtin_ctzll(mm); mm &= mm - 1;
                s += rlf(qsc, m) * ktb[((size_t)m << 11) + col];
            }
            const unsigned val = (col <= t) ? umap(s) : U_NEG_INF;
            sv[j] = val;
            rowmax = (val > rowmax) ? val : rowmax;
            if (dosel) atomicAdd(&hrow[rep + (val >> 24)], 1u);
        }
    }

#pragma unroll
    for (int o = 32; o; o >>= 1) {
        const unsigned m2 = __shfl_xor(rowmax, o);
        rowmax = (m2 > rowmax) ? m2 : rowmax;
    }
    const float fm = uunmap(rowmax);         // row max (finite: col 0 <= t)

    // ---- exact kth via radix-256 select (level 0 precomputed above) ----
    unsigned cur = U_NEG_INF;                // rows t<256 keep everything
    if (dosel) {
        unsigned prefix = 0u, pmask = 0u;
        unsigned r = KKEEP;
#pragma unroll 1
        for (int level = 0; level < 4; ++level) {
            const int sh = 24 - 8 * level;
            if (level) {                     // levels 1-3: single histogram
                hrow[lane] = 0; hrow[64 + lane] = 0;
                hrow[128 + lane] = 0; hrow[192 + lane] = 0;
                __asm__ volatile("s_waitcnt lgkmcnt(0)" ::: "memory");
#pragma unroll
                for (int j = 0; j < NJMAX; ++j) {
                    if (j < nj) {
                        const int col = (j << 6) + lane;
                        const unsigned v = sv[j];
                        if (col <= t && (v & pmask) == prefix)
                            atomicAdd(&hrow[(v >> sh) & 255u], 1u);
                    }
                }
            }
            __asm__ volatile("s_waitcnt lgkmcnt(0)" ::: "memory");
            uint4 hv = *(const uint4*)&hrow[lane * 4];     // bins 4l..4l+3
            if (level == 0) {                // sum the other 3 replicas
#pragma unroll
                for (int rr = 1; rr < 4; ++rr) {
                    const uint4 h2 = *(const uint4*)&hrow[rr * HREP + lane * 4];
                    hv.x += h2.x; hv.y += h2.y; hv.z += h2.z; hv.w += h2.w;
                }
            }
            const unsigned ls = hv.x + hv.y + hv.z + hv.w;
            unsigned sfx = ls;                    // inclusive suffix over lanes
#pragma unroll
            for (int off = 1; off < 64; off <<= 1) {
                const unsigned tt2 = __shfl_down(sfx, off);
                if (lane + off < 64) sfx += tt2;
            }
            const unsigned excl = sfx - ls;       // lanes strictly above
            const unsigned c3 = excl + hv.w, c2 = c3 + hv.z,
                           c1 = c2 + hv.y,  c0 = c1 + hv.x;
            int bsel = -1; unsigned csel = 0, cnext = 0;
            if      (c3 >= r) { bsel = 4 * lane + 3; csel = c3; cnext = excl; }
            else if (c2 >= r) { bsel = 4 * lane + 2; csel = c2; cnext = c3; }
            else if (c1 >= r) { bsel = 4 * lane + 1; csel = c1; cnext = c2; }
            else if (c0 >= r) { bsel = 4 * lane + 0; csel = c0; cnext = c1; }
            int B = bsel;
#pragma unroll
            for (int off = 32; off; off >>= 1) {
                const int ob = __shfl_xor(B, off);
                B = (ob > B) ? ob : B;
            }
            const unsigned cB  = (unsigned)__shfl((int)csel,  B >> 2);
            const unsigned cB1 = (unsigned)__shfl((int)cnext, B >> 2);
            prefix |= (unsigned)B << sh;
            pmask  |= 255u << sh;
            if (cB == r || level == 3) { cur = prefix; break; }
            r -= cB1;                    // rank within bin B
        }
    }

    // ---- FUSED softmax + compaction: packed (col, p) uint2 into LDS ----
    uint2* cp = cpk + w * 256;           // own row only: no cross-wave hazard
    float ps = 0.0f;
    int cnt = 0; bool ovf = false;
#pragma unroll
    for (int j = 0; j < NJMAX; ++j) {
        if (j >= nj) continue;
        const int col = (j << 6) + lane;
        float pv = 0.0f;
        const unsigned uv = sv[j];
        if (col <= t && uv >= cur) pv = __expf(uunmap(uv) - fm);
        ps += pv;
        const unsigned long long m = __ballot(pv > 0.0f);
        const int c = __popcll(m);
        if (cnt + c <= 256) {
            if (pv > 0.0f) {
                const int pos = cnt + __popcll(m & ((1ull << lane) - 1ull));
                cp[pos] = make_uint2((unsigned)col, __float_as_uint(pv));
            }
        } else ovf = true;
        cnt += c;
    }
#pragma unroll
    for (int o = 32; o; o >>= 1) ps += __shfl_xor(ps, o);
    const float inv = 1.0f / ps;         // ps >= 1 (row max is kept)

    if (!ovf) {
        // zero-fill tail entries so PV needs no per-entry guard
#pragma unroll
        for (int blk = 0; blk < 4; ++blk) {
            const int idx = blk * 64 + lane;
            if (idx >= cnt) cp[idx] = make_uint2(0u, 0u);
        }
        // PV: 4 dims/lane, 4 column-subgroups.  Subgroup g = lane>>4 handles
        // list entries 4j+g via ONE ds_read_b64 broadcast (same addr across
        // the 16-lane subgroup = conflict-free); lane loads V[c][d0..d0+3].
        const int g  = lane >> 4;
        const int d0 = (lane & 15) * 4;
        float ax = 0.0f, ay = 0.0f, az = 0.0f, aw = 0.0f;
        const float* __restrict__ vb4 = Vm + kvoff + d0;
#pragma unroll
        for (int blk = 0; blk < 4; ++blk) {
            if (cnt > blk * 64) {
#pragma unroll
                for (int j = 0; j < 16; ++j) {
                    const uint2 e = cp[blk * 64 + 4 * j + g];
                    const float p = __uint_as_float(e.y);
                    const float4 v4 = *(const float4*)&vb4[(size_t)e.x * Cn];
                    ax += p * v4.x; ay += p * v4.y;
                    az += p * v4.z; aw += p * v4.w;
                }
            }
        }
        // reduce across the 4 subgroups (lanes l, l^16, l^32, l^48)
#pragma unroll
        for (int o = 16; o <= 32; o <<= 1) {
            ax += __shfl_xor(ax, o);
            ay += __shfl_xor(ay, o);
            az += __shfl_xor(az, o);
            aw += __shfl_xor(aw, o);
        }
        if (g == 0) {
            const float vx = ax * inv, vy = ay * inv,
                        vz = az * inv, vw = aw * inv;
            const bfpair px = split_bf16(vx), py = split_bf16(vy),
                         pz = split_bf16(vz), pw = split_bf16(vw);
            ushort4 hq, lq;
            hq.x = px.h; hq.y = py.h; hq.z = pz.h; hq.w = pw.h;
            lq.x = px.l; lq.y = py.l; lq.z = pz.l; lq.w = pw.l;
            *(ushort4*)&AOH[rowoff + d0] = hq;
            *(ushort4*)&AOL[rowoff + d0] = lq;
        }
    } else {
        // tie-overflow fallback (rare): while(ballot) gather from sv regs
        const float* __restrict__ vcol = Vm + kvoff + lane;
        float acc = 0.0f;
#pragma unroll
        for (int j = 0; j < NJMAX; ++j) {
            if (j >= nj) continue;
            const int col = (j << 6) + lane;
            float pv = 0.0f;
            const unsigned uv = sv[j];
            if (col <= t && uv >= cur) pv = __expf(uunmap(uv) - fm);
            unsigned long long m = __ballot(pv > 0.0f);
            const int cb = j << 6;
            while (m) {
                const int l0 = __builtin_ctzll(m); m &= m - 1;
                const float w0 = __shfl(pv, l0);
                const float v0 = vcol[(size_t)(cb + l0) * Cn];
                float w1 = 0.0f, v1 = 0.0f;
                if (m) {
                    const int l1 = __builtin_ctzll(m); m &= m - 1;
                    w1 = __shfl(pv, l1);
                    v1 = vcol[(size_t)(cb + l1) * Cn];
                }
                acc += w0 * v0;
                acc += w1 * v1;
            }
        }
        const float v = acc * inv;
        const bfpair p = split_bf16(v);
        AOH[rowoff + lane] = p.h;
        AOL[rowoff + lane] = p.l;
    }
}

// ---------------------------------------------------------------------------
extern "C" void kernel_launch(void* const* d_in, const int* in_sizes, int n_in,
                              void* d_out, int out_size, void* d_ws, size_t ws_size,
                              hipStream_t stream)
{
    const float* x  = (const float*)d_in[0];
    const float* Wq = (const float*)d_in[1];
    const float* Wk = (const float*)d_in[2];
    const float* Wv = (const float*)d_in[3];
    const float* Wo = (const float*)d_in[4];
    float* out = (float*)d_out;

    // Workspace (4 x 16.8 MB): buf0=Q, buf1=K-dense (later AOH/AOL),
    // buf2=V, buf3=KT (holds Wq/k/v splits until step 3 overwrites).
    float* Q  = (float*)d_ws;
    float* K  = Q + (size_t)Mn * Cn;
    float* V  = K + (size_t)Mn * Cn;
    float* KT = V + (size_t)Mn * Cn;

    unsigned short* XH  = (unsigned short*)d_out;
    unsigned short* XL  = XH + (size_t)Mn * Cn;
    unsigned short* WHL = (unsigned short*)KT;
    unsigned short* AOH = (unsigned short*)K;
    unsigned short* AOL = AOH + (size_t)Mn * Cn;

    // 0) one-time hi/lo bf16 split of x and Wq/Wk/Wv
    presplit<<<dim3((unsigned)((XCHUNK + 3 * WCHUNK) / 256)), 256, 0, stream>>>(
        x, Wq, Wk, Wv, XH, XL, WHL);

    // 1) Q/K/V projections from pre-split operands (glds staging)
    gemm_qkv_ps<<<dim3(Cn / 128, Mn / 128, 3), 256, 0, stream>>>(
        XH, XL, WHL, Q, K, V);

    // 2) feature top-8 sparsification of Q and V, in place
    sparsify_topk<<<dim3(2 * 65536 / 4), 256, 0, stream>>>(Q, V);

    // 3) K sparsify + transpose -> KT[bh][d][t] (overwrites W splits)
    sparsify_k_t<<<dim3(32, 32), 256, 0, stream>>>(K, KT);

    // 4) sparse attention core -> split AOH/AOL (overwrites K-dense)
    attn_kernel<<<dim3(Tn / NW, 32), 256, 0, stream>>>(Q, KT, V, AOH, AOL);

    // 5) output projection (glds A, on-the-fly W split)
    gemm_out_ps<<<dim3(Cn / 128, Mn / 128, 1), 256, 0, stream>>>(
        AOH, AOL, Wo, out);
}

// Round 14
// 670.897 us; speedup vs baseline: 1.5317x; 1.1469x over previous
//
#include <hip/hip_runtime.h>
#include <cstdint>

// Problem constants: B=2, T=2048, C=1024, H=16, D=64, TOP_K=256
// feat_keep = ceil(D*min(TOP_K,T)/T) = ceil(64*256/2048) = 8
constexpr int Tn = 2048;
constexpr int Cn = 1024;
constexpr int Mn = 4096;          // B*T
constexpr int KKEEP = 256;        // row-wise top-k
constexpr int FKEEP = 8;          // feature top-k
constexpr unsigned U_NEG_INF = 0x007FFFFFu;  // umap(-inf)

constexpr int NW     = 4;         // waves (query rows) per attn block
constexpr int NJMAX  = 32;        // max 64-col groups per row (T/64)
// Level-0 histogram: 4 replicas at stride 260 words (260%32==4 -> replicas
// on banks +0/+4/+8/+12; same-bin atomics run on 4 banks in parallel).
constexpr int HREP   = 260;       // words between replicas
constexpr int HWAVE  = 4 * HREP;  // 1040 words per wave

// Order-preserving fp32 -> uint32 map (monotonic incl. +-inf; no NaNs here).
__device__ __forceinline__ unsigned umap(float f) {
    unsigned b = __float_as_uint(f);
    return (b & 0x80000000u) ? ~b : (b | 0x80000000u);
}
__device__ __forceinline__ float uunmap(unsigned u) {
    return __uint_as_float((u & 0x80000000u) ? (u ^ 0x80000000u) : ~u);
}

// fp32 -> bf16 (RNE).
__device__ __forceinline__ unsigned short f2bf(float f) {
    unsigned u = __float_as_uint(f);
    u += 0x7FFFu + ((u >> 16) & 1u);
    return (unsigned short)(u >> 16);
}
// Split fp32 into hi+lo bf16 pair.  x ~= hi + lo, ~17-bit effective mantissa.
struct bfpair { unsigned short h, l; };
__device__ __forceinline__ bfpair split_bf16(float x) {
    bfpair r;
    r.h = f2bf(x);
    r.l = f2bf(x - __uint_as_float((unsigned)r.h << 16));
    return r;
}

// Wave-uniform broadcasts on the SALU path (NOT ds_bpermute / LDS pipe).
__device__ __forceinline__ int   rli(int v, int l)   { return __builtin_amdgcn_readlane(v, l); }
__device__ __forceinline__ float rlf(float v, int l) {
    return __int_as_float(__builtin_amdgcn_readlane(__float_as_int(v), l));
}

// Async global->LDS, 16B per lane: lane l writes ldsbase + l*16 (linear).
__device__ __forceinline__ void glds16(const void* g, void* l) {
    __builtin_amdgcn_global_load_lds(
        (const __attribute__((address_space(1))) void*)g,
        (__attribute__((address_space(3))) void*)l, 16, 0, 0);
}

// R23: 8th-largest of 64 lane values via 21-step bitonic sort (ascending;
// result s[56] = 8th largest).  Replaces the 64-iteration count loop
// (70 ds_bpermute -> 22 LDS-pipe ops).  Threshold PROVABLY equals the old
// min{a : #greater < 8}: any a < s[56] has >=8 strictly greater (s[57..63]
// ...wait, ascending: s[57..63] >= s[56] are 7 elems; elements s[56..63]
// are the top 8; a < s[56] -> at least the 8 values s[56..63] > a).
// Ties included both ways -> identical keep-set -> bit-identical output.
__device__ __forceinline__ float topk8_thresh(float a, int lane) {
    float s = a;
#pragma unroll
    for (int k = 2; k <= 64; k <<= 1) {
#pragma unroll
        for (int j = k >> 1; j > 0; j >>= 1) {
            const float o = __shfl_xor(s, j);
            const bool dirUp   = (lane & k) == 0;   // k=64: always true
            const bool takeMin = dirUp == ((lane & j) == 0);
            s = takeMin ? fminf(s, o) : fmaxf(s, o);
        }
    }
    return __shfl(s, 56);                    // ascending rank 56 = 8th largest
}

typedef __attribute__((ext_vector_type(8))) short          short8v;  // 8 bf16
typedef __attribute__((ext_vector_type(8))) unsigned short ushort8v;
typedef __attribute__((ext_vector_type(4))) float          f32x4;    // MFMA acc

// ---------------------------------------------------------------------------
// Pre-split pass (R18): x -> XH/XL (d_out scratch), Wq/Wk/Wv -> packed hi/lo
// (KT-buffer scratch) ONCE.  Identical f2bf math -> downstream bit-identical.
// ---------------------------------------------------------------------------
constexpr size_t XCHUNK = (size_t)Mn * Cn / 8;      // 524288 8-elem chunks
constexpr size_t WCHUNK = (size_t)Cn * Cn / 8;      // 131072 per matrix
constexpr size_t WELEMS = (size_t)Cn * Cn;          // 1048576

__device__ __forceinline__ void split8(const float* s, unsigned short* dh,
                                       unsigned short* dl, size_t base)
{
    const float4 a = *(const float4*)&s[base], b = *(const float4*)&s[base + 4];
    ushort8v h, l; bfpair p;
    p = split_bf16(a.x); h[0] = p.h; l[0] = p.l;
    p = split_bf16(a.y); h[1] = p.h; l[1] = p.l;
    p = split_bf16(a.z); h[2] = p.h; l[2] = p.l;
    p = split_bf16(a.w); h[3] = p.h; l[3] = p.l;
    p = split_bf16(b.x); h[4] = p.h; l[4] = p.l;
    p = split_bf16(b.y); h[5] = p.h; l[5] = p.l;
    p = split_bf16(b.z); h[6] = p.h; l[6] = p.l;
    p = split_bf16(b.w); h[7] = p.h; l[7] = p.l;
    *(ushort8v*)&dh[base] = h;
    *(ushort8v*)&dl[base] = l;
}

__global__ __launch_bounds__(256)
void presplit(const float* __restrict__ x,  const float* __restrict__ Wq,
              const float* __restrict__ Wk, const float* __restrict__ Wv,
              unsigned short* __restrict__ XH, unsigned short* __restrict__ XL,
              unsigned short* __restrict__ WHL)
{
    const size_t cid = (size_t)blockIdx.x * 256 + threadIdx.x;
    if (cid < XCHUNK) {
        split8(x, XH, XL, cid * 8);
    } else {
        const size_t c2 = cid - XCHUNK;
        const int    z  = (int)(c2 / WCHUNK);        // 0..2
        const size_t e  = (c2 % WCHUNK) * 8;
        const float* src = (z == 0) ? Wq : (z == 1 ? Wk : Wv);
        unsigned short* dh = WHL + (size_t)z * 2 * WELEMS;
        unsigned short* dl = dh + WELEMS;
        split8(src, dh, dl, e);
    }
}

// ---------------------------------------------------------------------------
// QKV GEMM (R22): pre-split operands staged via async global_load_lds
// (width=16) into UNPADDED [128][32] LDS.  Bit-identical MFMA sequence.
// ---------------------------------------------------------------------------
__global__ __launch_bounds__(256, 2)
void gemm_qkv_ps(const unsigned short* __restrict__ XH,
                 const unsigned short* __restrict__ XL,
                 const unsigned short* __restrict__ WHL,
                 float* __restrict__ O0, float* __restrict__ O1,
                 float* __restrict__ O2)
{
    const int z = blockIdx.z;
    const unsigned short* WH = WHL + (size_t)z * 2 * WELEMS;
    const unsigned short* WL = WH + WELEMS;
    float* O = (z == 0) ? O0 : (z == 1 ? O1 : O2);

    __shared__ unsigned short Ah[128][32], Al[128][32];   // 4 x 8 KB
    __shared__ unsigned short Bh[128][32], Bl[128][32];

    const int tid  = threadIdx.x;
    const int lane = tid & 63;
    const int wv   = tid >> 6;
    const int wm   = wv >> 1, wn = wv & 1;
    const int fm   = lane & 15;
    const int fq   = lane >> 4;
    const int m0   = blockIdx.y * 128;
    const int n0   = blockIdx.x * 128;

    const int srow = lane >> 2;
    const int se0  = (lane & 3) * 8;

    f32x4 acc[4][4] = {};

    for (int k0 = 0; k0 < Cn; k0 += 32) {
        __syncthreads();
#pragma unroll
        for (int c = 0; c < 2; ++c) {
            const int rb  = wv * 32 + c * 16;        // slab row base
            const int row = rb + srow;
            const size_t ao = (size_t)(m0 + row) * Cn + k0 + se0;
            const size_t bo = (size_t)(n0 + row) * Cn + k0 + se0;
            glds16(XH + ao, &Ah[rb][0]);
            glds16(XL + ao, &Al[rb][0]);
            glds16(WH + bo, &Bh[rb][0]);
            glds16(WL + bo, &Bl[rb][0]);
        }
        __syncthreads();   // vmcnt(0) drain: all glds landed

        short8v ah[4], al[4], bh[4], bl[4];
#pragma unroll
        for (int ti = 0; ti < 4; ++ti) {
            ah[ti] = *(const short8v*)&Ah[wm * 64 + ti * 16 + fm][fq * 8];
            al[ti] = *(const short8v*)&Al[wm * 64 + ti * 16 + fm][fq * 8];
            bh[ti] = *(const short8v*)&Bh[wn * 64 + ti * 16 + fm][fq * 8];
            bl[ti] = *(const short8v*)&Bl[wn * 64 + ti * 16 + fm][fq * 8];
        }
#pragma unroll
        for (int ti = 0; ti < 4; ++ti)
#pragma unroll
            for (int tj = 0; tj < 4; ++tj) {
                acc[ti][tj] = __builtin_amdgcn_mfma_f32_16x16x32_bf16(
                    ah[ti], bh[tj], acc[ti][tj], 0, 0, 0);
                acc[ti][tj] = __builtin_amdgcn_mfma_f32_16x16x32_bf16(
                    ah[ti], bl[tj], acc[ti][tj], 0, 0, 0);
                acc[ti][tj] = __builtin_amdgcn_mfma_f32_16x16x32_bf16(
                    al[ti], bh[tj], acc[ti][tj], 0, 0, 0);
            }
    }

#pragma unroll
    for (int ti = 0; ti < 4; ++ti)
#pragma unroll
        for (int tj = 0; tj < 4; ++tj)
#pragma unroll
            for (int r = 0; r < 4; ++r) {
                const int row = m0 + wm * 64 + ti * 16 + fq * 4 + r;
                const int col = n0 + wn * 64 + tj * 16 + fm;
                O[(size_t)row * Cn + col] = acc[ti][tj][r];
            }
}

// ---------------------------------------------------------------------------
// Out-proj GEMM (R22): A (pre-split AOH/AOL) via glds into unpadded LDS;
// Wo split on the fly into padded LDS.  Bit-identical math.
// ---------------------------------------------------------------------------
__global__ __launch_bounds__(256, 2)
void gemm_out_ps(const unsigned short* __restrict__ AH,
                 const unsigned short* __restrict__ AL,
                 const float* __restrict__ Wo, float* __restrict__ O)
{
    __shared__ unsigned short Ah[128][32], Al[128][32];   // glds, linear
    __shared__ unsigned short Bh[128][40], Bl[128][40];   // VALU-split, padded

    const int tid  = threadIdx.x;
    const int lane = tid & 63;
    const int wv   = tid >> 6;
    const int wm   = wv >> 1, wn = wv & 1;
    const int fm   = lane & 15;
    const int fq   = lane >> 4;
    const int m0   = blockIdx.y * 128;
    const int n0   = blockIdx.x * 128;

    const int srow = lane >> 2;
    const int se0  = (lane & 3) * 8;

    f32x4 acc[4][4] = {};

    for (int k0 = 0; k0 < Cn; k0 += 32) {
        __syncthreads();
#pragma unroll
        for (int c = 0; c < 2; ++c) {
            const int rb  = wv * 32 + c * 16;
            const int row = rb + srow;
            const size_t ao = (size_t)(m0 + row) * Cn + k0 + se0;
            glds16(AH + ao, &Ah[rb][0]);
            glds16(AL + ao, &Al[rb][0]);
        }
#pragma unroll
        for (int r = 0; r < 2; ++r) {
            const int idx = tid + r * 256;
            const int row = idx >> 2, c8 = (idx & 3) * 8;
            const float* s = &Wo[(size_t)(n0 + row) * Cn + k0 + c8];
            const float4 x0 = *(const float4*)s, x1 = *(const float4*)(s + 4);
            ushort8v h, l;
            bfpair p;
            p = split_bf16(x0.x); h[0] = p.h; l[0] = p.l;
            p = split_bf16(x0.y); h[1] = p.h; l[1] = p.l;
            p = split_bf16(x0.z); h[2] = p.h; l[2] = p.l;
            p = split_bf16(x0.w); h[3] = p.h; l[3] = p.l;
            p = split_bf16(x1.x); h[4] = p.h; l[4] = p.l;
            p = split_bf16(x1.y); h[5] = p.h; l[5] = p.l;
            p = split_bf16(x1.z); h[6] = p.h; l[6] = p.l;
            p = split_bf16(x1.w); h[7] = p.h; l[7] = p.l;
            *(ushort8v*)&Bh[row][c8] = h;
            *(ushort8v*)&Bl[row][c8] = l;
        }
        __syncthreads();

        short8v ah[4], al[4], bh[4], bl[4];
#pragma unroll
        for (int ti = 0; ti < 4; ++ti) {
            ah[ti] = *(const short8v*)&Ah[wm * 64 + ti * 16 + fm][fq * 8];
            al[ti] = *(const short8v*)&Al[wm * 64 + ti * 16 + fm][fq * 8];
            bh[ti] = *(const short8v*)&Bh[wn * 64 + ti * 16 + fm][fq * 8];
            bl[ti] = *(const short8v*)&Bl[wn * 64 + ti * 16 + fm][fq * 8];
        }
#pragma unroll
        for (int ti = 0; ti < 4; ++ti)
#pragma unroll
            for (int tj = 0; tj < 4; ++tj) {
                acc[ti][tj] = __builtin_amdgcn_mfma_f32_16x16x32_bf16(
                    ah[ti], bh[tj], acc[ti][tj], 0, 0, 0);
                acc[ti][tj] = __builtin_amdgcn_mfma_f32_16x16x32_bf16(
                    ah[ti], bl[tj], acc[ti][tj], 0, 0, 0);
                acc[ti][tj] = __builtin_amdgcn_mfma_f32_16x16x32_bf16(
                    al[ti], bh[tj], acc[ti][tj], 0, 0, 0);
            }
    }

#pragma unroll
    for (int ti = 0; ti < 4; ++ti)
#pragma unroll
        for (int tj = 0; tj < 4; ++tj)
#pragma unroll
            for (int r = 0; r < 4; ++r) {
                const int row = m0 + wm * 64 + ti * 16 + fq * 4 + r;
                const int col = n0 + wn * 64 + tj * 16 + fm;
                O[(size_t)row * Cn + col] = acc[ti][tj][r];
            }
}

// ---------------------------------------------------------------------------
// Feature sparsify for Q and V (in place), R23: bitonic-sort threshold
// (21 shfl_xor + 1 shfl vs 64 shfl + 6 shfl_xor).  Identical keep-set.
// ---------------------------------------------------------------------------
__global__ __launch_bounds__(256)
void sparsify_topk(float* __restrict__ Q, float* __restrict__ V)
{
    const int wid  = (blockIdx.x * 256 + threadIdx.x) >> 6;  // global wave id
    const int lane = threadIdx.x & 63;
    const int tensor = wid >> 16;        // 0=Q, 1=V
    const int vec    = wid & 65535;
    float* base = tensor ? V : Q;

    const size_t off = (size_t)vec * 64 + lane;
    const float v = base[off];
    const float a = fabsf(v);

    const float thresh = topk8_thresh(a, lane);
    base[off] = (a >= thresh) ? v : 0.0f;
}

// ---------------------------------------------------------------------------
// K sparsify + transpose: K[b][t][h][d] -> KT[bh][d][t].  R23: bitonic
// threshold per row (same keep-set as before -> bit-identical KT).
// ---------------------------------------------------------------------------
__global__ __launch_bounds__(256)
void sparsify_k_t(const float* __restrict__ K, float* __restrict__ KT)
{
    __shared__ float tile[64][65];       // [t-row][d], pad 65

    const int tid = threadIdx.x;
    const int w = tid >> 6, lane = tid & 63;
    const int tt = blockIdx.x;           // t-tile 0..31
    const int bh = blockIdx.y;           // 0..31
    const int b = bh >> 4, h = bh & 15;
    const int t0 = tt * 64;

#pragma unroll
    for (int k = 0; k < 4; ++k) {
        const int c = tid + k * 256;     // 0..1023 float4-chunks
        const int row = c >> 4, off = (c & 15) * 4;
        const float4 v4 = *(const float4*)
            &K[(size_t)((b * Tn + t0 + row) * 16 + h) * 64 + off];
        tile[row][off + 0] = v4.x; tile[row][off + 1] = v4.y;
        tile[row][off + 2] = v4.z; tile[row][off + 3] = v4.w;
    }
    __syncthreads();

#pragma unroll 1
    for (int r = w; r < 64; r += 4) {
        const float v = tile[r][lane];
        const float a = fabsf(v);
        const float thresh = topk8_thresh(a, lane);
        tile[r][lane] = (a >= thresh) ? v : 0.0f;
    }
    __syncthreads();

#pragma unroll
    for (int k = 0; k < 16; ++k) {
        const int d = w + k * 4;
        KT[(((size_t)bh * 64 + d) << 11) + t0 + lane] = tile[lane][d];
    }
}

// ---------------------------------------------------------------------------
// Attention core, unchanged from R21 (best: ~448us; bank-rotated level-0
// histogram replicas + packed uint2 compaction + fused level-0 atomics).
// ---------------------------------------------------------------------------
__global__ __launch_bounds__(256, 4)
void attn_kernel(const float* __restrict__ Qm, const float* __restrict__ KTm,
                 const float* __restrict__ Vm,
                 unsigned short* __restrict__ AOH,
                 unsigned short* __restrict__ AOL)
{
    __shared__ unsigned hist[NW * HWAVE];    // 4 bank-rotated replicas / wave
    __shared__ uint2    cpk[NW * 256];       // compacted (col, p) (per wave)

    const int tid  = threadIdx.x;
    const int w    = tid >> 6;
    const int lane = tid & 63;
    const int bh   = blockIdx.y;             // 0..31
    const int b    = bh >> 4;
    const int h    = bh & 15;
    const int t    = blockIdx.x * NW + w;
    const size_t rowoff = ((size_t)(b * Tn + t) << 10) + (h << 6);
    const size_t kvoff  = ((size_t)(b * Tn) << 10) + (h << 6);

    // ---- sparse q row in a register; nonzero feature mask (wave-uniform) ----
    const float q0  = Qm[rowoff + lane];
    const float qsc = q0 * 0.125f;                  // fold 1/sqrt(D)
    const unsigned long long nzm = __ballot(q0 != 0.0f);
    const int nnz = __popcll(nzm);                  // wave-uniform, ==8 a.s.

    const int nj = (t >> 6) + 1;             // visible 64-col groups
    const float* ktb = KTm + ((size_t)bh << 17);    // [d][t] slice

    const bool dosel = (t >= KKEEP);         // wave-uniform
    unsigned* hrow = hist + w * HWAVE;       // replica 0 (levels 1-3 use this)
    const int rep = (lane >> 4) * HREP;      // this lane's level-0 replica
    // zero ALL 4 replicas' bins BEFORE the score pass (level-0 fused below)
#pragma unroll
    for (int rr = 0; rr < 4; ++rr) {
        hrow[rr * HREP +   0 + lane] = 0; hrow[rr * HREP +  64 + lane] = 0;
        hrow[rr * HREP + 128 + lane] = 0; hrow[rr * HREP + 192 + lane] = 0;
    }
    __asm__ volatile("s_waitcnt lgkmcnt(0)" ::: "memory");

    // ---- score row in registers: sv[j] = umap(score of col j*64+lane) ----
    // Level-0 histogram atomics issued inline (hide under load stalls),
    // scattered across the lane's bank-rotated replica.
    unsigned sv[NJMAX];
    unsigned rowmax = 0u;
    if (nnz == 8) {
        float mq[8]; int moff[8];
        {
            unsigned long long mm = nzm;
#pragma unroll
            for (int i = 0; i < 8; ++i) {
                const int m = (int)__builtin_ctzll(mm); mm &= mm - 1;
                mq[i] = rlf(qsc, m);
                moff[i] = m << 11;
            }
        }
#pragma unroll
        for (int jq = 0; jq < NJMAX / 4; ++jq) {
            const int j0 = jq * 4;
            if (j0 >= nj) {
                sv[j0] = U_NEG_INF; sv[j0 + 1] = U_NEG_INF;
                sv[j0 + 2] = U_NEG_INF; sv[j0 + 3] = U_NEG_INF;
                continue;
            }
            const int c0 = (j0 << 6) + lane;
            if (j0 + 4 <= nj) {              // full quad: 32 loads in flight
                float s0 = 0.0f, s1 = 0.0f, s2 = 0.0f, s3 = 0.0f;
#pragma unroll
                for (int i = 0; i < 8; ++i) {
                    const float* kpi = ktb + moff[i];
                    s0 += mq[i] * kpi[c0];
                    s1 += mq[i] * kpi[c0 + 64];
                    s2 += mq[i] * kpi[c0 + 128];
                    s3 += mq[i] * kpi[c0 + 192];
                }
                const unsigned v0 = (c0       <= t) ? umap(s0) : U_NEG_INF;
                const unsigned v1 = (c0 +  64 <= t) ? umap(s1) : U_NEG_INF;
                const unsigned v2 = (c0 + 128 <= t) ? umap(s2) : U_NEG_INF;
                const unsigned v3 = (c0 + 192 <= t) ? umap(s3) : U_NEG_INF;
                sv[j0] = v0; sv[j0 + 1] = v1; sv[j0 + 2] = v2; sv[j0 + 3] = v3;
                unsigned m01 = (v0 > v1) ? v0 : v1;
                unsigned m23 = (v2 > v3) ? v2 : v3;
                m01 = (m01 > m23) ? m01 : m23;
                rowmax = (m01 > rowmax) ? m01 : rowmax;
                if (dosel) {                 // fused level-0 histogram
                    atomicAdd(&hrow[rep + (v0 >> 24)], 1u);
                    atomicAdd(&hrow[rep + (v1 >> 24)], 1u);
                    atomicAdd(&hrow[rep + (v2 >> 24)], 1u);
                    atomicAdd(&hrow[rep + (v3 >> 24)], 1u);
                }
            } else {                         // partial quad tail
#pragma unroll
                for (int k = 0; k < 4; ++k) {
                    const int j = j0 + k;
                    if (j < nj) {
                        const int col = (j << 6) + lane;
                        float s = 0.0f;
#pragma unroll
                        for (int i = 0; i < 8; ++i)
                            s += mq[i] * ktb[moff[i] + col];
                        const unsigned v = (col <= t) ? umap(s) : U_NEG_INF;
                        sv[j] = v;
                        rowmax = (v > rowmax) ? v : rowmax;
                        if (dosel) atomicAdd(&hrow[rep + (v >> 24)], 1u);
                    } else sv[j] = U_NEG_INF;
                }
            }
        }
    } else {
        // generic fallback (magnitude ties -> nnz > 8): rare, wave-uniform
#pragma unroll
        for (int j = 0; j < NJMAX; ++j) {
            if (j >= nj) { sv[j] = U_NEG_INF; continue; }
            const int col = (j << 6) + lane;
            float s = 0.0f;
            unsigned long long mm = nzm;
            while (mm) {
                const int m = (int)__builtin_ctzll(mm); mm &= mm - 1;
                s += rlf(qsc, m) * ktb[((size_t)m << 11) + col];
            }
            const unsigned val = (col <= t) ? umap(s) : U_NEG_INF;
            sv[j] = val;
            rowmax = (val > rowmax) ? val : rowmax;
            if (dosel) atomicAdd(&hrow[rep + (val >> 24)], 1u);
        }
    }

#pragma unroll
    for (int o = 32; o; o >>= 1) {
        const unsigned m2 = __shfl_xor(rowmax, o);
        rowmax = (m2 > rowmax) ? m2 : rowmax;
    }
    const float fm = uunmap(rowmax);         // row max (finite: col 0 <= t)

    // ---- exact kth via radix-256 select (level 0 precomputed above) ----
    unsigned cur = U_NEG_INF;                // rows t<256 keep everything
    if (dosel) {
        unsigned prefix = 0u, pmask = 0u;
        unsigned r = KKEEP;
#pragma unroll 1
        for (int level = 0; level < 4; ++level) {
            const int sh = 24 - 8 * level;
            if (level) {                     // levels 1-3: single histogram
                hrow[lane] = 0; hrow[64 + lane] = 0;
                hrow[128 + lane] = 0; hrow[192 + lane] = 0;
                __asm__ volatile("s_waitcnt lgkmcnt(0)" ::: "memory");
#pragma unroll
                for (int j = 0; j < NJMAX; ++j) {
                    if (j < nj) {
                        const int col = (j << 6) + lane;
                        const unsigned v = sv[j];
                        if (col <= t && (v & pmask) == prefix)
                            atomicAdd(&hrow[(v >> sh) & 255u], 1u);
                    }
                }
            }
            __asm__ volatile("s_waitcnt lgkmcnt(0)" ::: "memory");
            uint4 hv = *(const uint4*)&hrow[lane * 4];     // bins 4l..4l+3
            if (level == 0) {                // sum the other 3 replicas
#pragma unroll
                for (int rr = 1; rr < 4; ++rr) {
                    const uint4 h2 = *(const uint4*)&hrow[rr * HREP + lane * 4];
                    hv.x += h2.x; hv.y += h2.y; hv.z += h2.z; hv.w += h2.w;
                }
            }
            const unsigned ls = hv.x + hv.y + hv.z + hv.w;
            unsigned sfx = ls;                    // inclusive suffix over lanes
#pragma unroll
            for (int off = 1; off < 64; off <<= 1) {
                const unsigned tt2 = __shfl_down(sfx, off);
                if (lane + off < 64) sfx += tt2;
            }
            const unsigned excl = sfx - ls;       // lanes strictly above
            const unsigned c3 = excl + hv.w, c2 = c3 + hv.z,
                           c1 = c2 + hv.y,  c0 = c1 + hv.x;
            int bsel = -1; unsigned csel = 0, cnext = 0;
            if      (c3 >= r) { bsel = 4 * lane + 3; csel = c3; cnext = excl; }
            else if (c2 >= r) { bsel = 4 * lane + 2; csel = c2; cnext = c3; }
            else if (c1 >= r) { bsel = 4 * lane + 1; csel = c1; cnext = c2; }
            else if (c0 >= r) { bsel = 4 * lane + 0; csel = c0; cnext = c1; }
            int B = bsel;
#pragma unroll
            for (int off = 32; off; off >>= 1) {
                const int ob = __shfl_xor(B, off);
                B = (ob > B) ? ob : B;
            }
            const unsigned cB  = (unsigned)__shfl((int)csel,  B >> 2);
            const unsigned cB1 = (unsigned)__shfl((int)cnext, B >> 2);
            prefix |= (unsigned)B << sh;
            pmask  |= 255u << sh;
            if (cB == r || level == 3) { cur = prefix; break; }
            r -= cB1;                    // rank within bin B
        }
    }

    // ---- FUSED softmax + compaction: packed (col, p) uint2 into LDS ----
    uint2* cp = cpk + w * 256;           // own row only: no cross-wave hazard
    float ps = 0.0f;
    int cnt = 0; bool ovf = false;
#pragma unroll
    for (int j = 0; j < NJMAX; ++j) {
        if (j >= nj) continue;
        const int col = (j << 6) + lane;
        float pv = 0.0f;
        const unsigned uv = sv[j];
        if (col <= t && uv >= cur) pv = __expf(uunmap(uv) - fm);
        ps += pv;
        const unsigned long long m = __ballot(pv > 0.0f);
        const int c = __popcll(m);
        if (cnt + c <= 256) {
            if (pv > 0.0f) {
                const int pos = cnt + __popcll(m & ((1ull << lane) - 1ull));
                cp[pos] = make_uint2((unsigned)col, __float_as_uint(pv));
            }
        } else ovf = true;
        cnt += c;
    }
#pragma unroll
    for (int o = 32; o; o >>= 1) ps += __shfl_xor(ps, o);
    const float inv = 1.0f / ps;         // ps >= 1 (row max is kept)

    if (!ovf) {
        // zero-fill tail entries so PV needs no per-entry guard
#pragma unroll
        for (int blk = 0; blk < 4; ++blk) {
            const int idx = blk * 64 + lane;
            if (idx >= cnt) cp[idx] = make_uint2(0u, 0u);
        }
        // PV: 4 dims/lane, 4 column-subgroups.  Subgroup g = lane>>4 handles
        // list entries 4j+g via ONE ds_read_b64 broadcast (same addr across
        // the 16-lane subgroup = conflict-free); lane loads V[c][d0..d0+3].
        const int g  = lane >> 4;
        const int d0 = (lane & 15) * 4;
        float ax = 0.0f, ay = 0.0f, az = 0.0f, aw = 0.0f;
        const float* __restrict__ vb4 = Vm + kvoff + d0;
#pragma unroll
        for (int blk = 0; blk < 4; ++blk) {
            if (cnt > blk * 64) {
#pragma unroll
                for (int j = 0; j < 16; ++j) {
                    const uint2 e = cp[blk * 64 + 4 * j + g];
                    const float p = __uint_as_float(e.y);
                    const float4 v4 = *(const float4*)&vb4[(size_t)e.x * Cn];
                    ax += p * v4.x; ay += p * v4.y;
                    az += p * v4.z; aw += p * v4.w;
                }
            }
        }
        // reduce across the 4 subgroups (lanes l, l^16, l^32, l^48)
#pragma unroll
        for (int o = 16; o <= 32; o <<= 1) {
            ax += __shfl_xor(ax, o);
            ay += __shfl_xor(ay, o);
            az += __shfl_xor(az, o);
            aw += __shfl_xor(aw, o);
        }
        if (g == 0) {
            const float vx = ax * inv, vy = ay * inv,
                        vz = az * inv, vw = aw * inv;
            const bfpair px = split_bf16(vx), py = split_bf16(vy),
                         pz = split_bf16(vz), pw = split_bf16(vw);
            ushort4 hq, lq;
            hq.x = px.h; hq.y = py.h; hq.z = pz.h; hq.w = pw.h;
            lq.x = px.l; lq.y = py.l; lq.z = pz.l; lq.w = pw.l;
            *(ushort4*)&AOH[rowoff + d0] = hq;
            *(ushort4*)&AOL[rowoff + d0] = lq;
        }
    } else {
        // tie-overflow fallback (rare): while(ballot) gather from sv regs
        const float* __restrict__ vcol = Vm + kvoff + lane;
        float acc = 0.0f;
#pragma unroll
        for (int j = 0; j < NJMAX; ++j) {
            if (j >= nj) continue;
            const int col = (j << 6) + lane;
            float pv = 0.0f;
            const unsigned uv = sv[j];
            if (col <= t && uv >= cur) pv = __expf(uunmap(uv) - fm);
            unsigned long long m = __ballot(pv > 0.0f);
            const int cb = j << 6;
            while (m) {
                const int l0 = __builtin_ctzll(m); m &= m - 1;
                const float w0 = __shfl(pv, l0);
                const float v0 = vcol[(size_t)(cb + l0) * Cn];
                float w1 = 0.0f, v1 = 0.0f;
                if (m) {
                    const int l1 = __builtin_ctzll(m); m &= m - 1;
                    w1 = __shfl(pv, l1);
                    v1 = vcol[(size_t)(cb + l1) * Cn];
                }
                acc += w0 * v0;
                acc += w1 * v1;
            }
        }
        const float v = acc * inv;
        const bfpair p = split_bf16(v);
        AOH[rowoff + lane] = p.h;
        AOL[rowoff + lane] = p.l;
    }
}

// ---------------------------------------------------------------------------
extern "C" void kernel_launch(void* const* d_in, const int* in_sizes, int n_in,
                              void* d_out, int out_size, void* d_ws, size_t ws_size,
                              hipStream_t stream)
{
    const float* x  = (const float*)d_in[0];
    const float* Wq = (const float*)d_in[1];
    const float* Wk = (const float*)d_in[2];
    const float* Wv = (const float*)d_in[3];
    const float* Wo = (const float*)d_in[4];
    float* out = (float*)d_out;

    // Workspace (4 x 16.8 MB): buf0=Q, buf1=K-dense (later AOH/AOL),
    // buf2=V, buf3=KT (holds Wq/k/v splits until step 3 overwrites).
    float* Q  = (float*)d_ws;
    float* K  = Q + (size_t)Mn * Cn;
    float* V  = K + (size_t)Mn * Cn;
    float* KT = V + (size_t)Mn * Cn;

    unsigned short* XH  = (unsigned short*)d_out;
    unsigned short* XL  = XH + (size_t)Mn * Cn;
    unsigned short* WHL = (unsigned short*)KT;
    unsigned short* AOH = (unsigned short*)K;
    unsigned short* AOL = AOH + (size_t)Mn * Cn;

    // 0) one-time hi/lo bf16 split of x and Wq/Wk/Wv
    presplit<<<dim3((unsigned)((XCHUNK + 3 * WCHUNK) / 256)), 256, 0, stream>>>(
        x, Wq, Wk, Wv, XH, XL, WHL);

    // 1) Q/K/V projections from pre-split operands (glds staging)
    gemm_qkv_ps<<<dim3(Cn / 128, Mn / 128, 3), 256, 0, stream>>>(
        XH, XL, WHL, Q, K, V);

    // 2) feature top-8 sparsification of Q and V, in place (bitonic)
    sparsify_topk<<<dim3(2 * 65536 / 4), 256, 0, stream>>>(Q, V);

    // 3) K sparsify + transpose -> KT[bh][d][t] (overwrites W splits)
    sparsify_k_t<<<dim3(32, 32), 256, 0, stream>>>(K, KT);

    // 4) sparse attention core -> split AOH/AOL (overwrites K-dense)
    attn_kernel<<<dim3(Tn / NW, 32), 256, 0, stream>>>(Q, KT, V, AOH, AOL);

    // 5) output projection (glds A, on-the-fly W split)
    gemm_out_ps<<<dim3(Cn / 128, Mn / 128, 1), 256, 0, stream>>>(
        AOH, AOL, Wo, out);
}